// Round 22
// baseline (190.978 us; speedup 1.0000x reference)
//
#include <hip/hip_runtime.h>
#include <hip/hip_bf16.h>

#define NH 16
#define DK 64
#define SEQ 2048
#define DMODEL 1024
#define BATCH 2
#define MROWS (BATCH * SEQ) /* 4096 */

using bf16x8 = __attribute__((ext_vector_type(8))) short;
using f32x4  = __attribute__((ext_vector_type(4))) float;

#define NEGI (-1e30f)
#define QSCALE 0.18033688f  /* 0.125 * log2(e): folds 1/sqrt(dk) and exp->exp2 */

static __device__ __forceinline__ unsigned short f2bf(float x) {
  unsigned u = __builtin_bit_cast(unsigned, x);
  u += 0x7fffu + ((u >> 16) & 1u);   // RNE
  return (unsigned short)(u >> 16);
}
static __device__ __forceinline__ float bf2f(unsigned short h) {
  unsigned u = ((unsigned)h) << 16;
  return __builtin_bit_cast(float, u);
}
// packed f32x2 -> bf16x2 (lo = a, hi = b), single VALU inst
static __device__ __forceinline__ unsigned cvtpk(float a, float b) {
  unsigned r;
  asm("v_cvt_pk_bf16_f32 %0, %1, %2" : "=v"(r) : "v"(a), "v"(b));
  return r;
}
// async global->LDS, 16B per lane; LDS dest is wave-uniform base + lane*16
static __device__ __forceinline__ void gl_lds16(const unsigned short* g,
                                                unsigned short* l) {
  __builtin_amdgcn_global_load_lds(
      (const __attribute__((address_space(1))) unsigned int*)g,
      (__attribute__((address_space(3))) unsigned int*)l, 16, 0, 0);
}

static __device__ __forceinline__ void conv8(const float* s, unsigned short* d, long i) {
  const float* p = s + i * 8;
  float4 a = *(const float4*)(p);
  float4 b = *(const float4*)(p + 4);
  uint4 u = {cvtpk(a.x, a.y), cvtpk(a.z, a.w), cvtpk(b.x, b.y), cvtpk(b.z, b.w)};
  *(bf16x8*)(d + i * 8) = __builtin_bit_cast(bf16x8, u);
}

// ---------------------------------------------------------------- prep
// One launch: f32->bf16 converts (Q,K,V,Wq,Wk,Wv,Wo,biases) + mask packing.
// blocks [0,1536): QKV (512 each) | [1536,2048): W's (128 each)
// [2048,2560): pack_mask | 2560: biases
__global__ __launch_bounds__(256) void prep(const float* __restrict__ q,
                                            const float* __restrict__ k,
                                            const float* __restrict__ v,
                                            const float* __restrict__ wq,
                                            const float* __restrict__ wk,
                                            const float* __restrict__ wv,
                                            const float* __restrict__ wo,
                                            const float* __restrict__ bq,
                                            const float* __restrict__ bk,
                                            const float* __restrict__ bv,
                                            const float* __restrict__ bo,
                                            const int* __restrict__ mask,
                                            unsigned short* __restrict__ Qc,
                                            unsigned short* __restrict__ Kc,
                                            unsigned short* __restrict__ Vc,
                                            unsigned short* __restrict__ Wqc,
                                            unsigned short* __restrict__ Wkc,
                                            unsigned short* __restrict__ Wvc,
                                            unsigned short* __restrict__ Woc,
                                            unsigned short* __restrict__ bqc,
                                            unsigned short* __restrict__ bkc,
                                            unsigned short* __restrict__ bvc,
                                            unsigned short* __restrict__ boc,
                                            unsigned long long* __restrict__ pm) {
  const int bid = blockIdx.x;
  const int t   = threadIdx.x;
  const long nQKV8 = (long)MROWS * DMODEL / 8;   // 524288
  const long nW8   = (long)DMODEL * DMODEL / 8;  // 131072
  if (bid < 1536) {                       // QKV converts
    int seg = bid >> 9;                   // /512
    int ib  = bid & 511;
    const float* s = seg == 0 ? q : (seg == 1 ? k : v);
    unsigned short* d = seg == 0 ? Qc : (seg == 1 ? Kc : Vc);
    long i0 = (long)ib * 256 + t;
    for (long i = i0; i < nQKV8; i += 512 * 256) conv8(s, d, i);
  } else if (bid < 2048) {                // W converts
    int seg = (bid - 1536) >> 7;          // /128
    int ib  = (bid - 1536) & 127;
    const float* s = seg == 0 ? wq : (seg == 1 ? wk : (seg == 2 ? wv : wo));
    unsigned short* d = seg == 0 ? Wqc : (seg == 1 ? Wkc : (seg == 2 ? Wvc : Woc));
    long i0 = (long)ib * 256 + t;
    for (long i = i0; i < nW8; i += 128 * 256) conv8(s, d, i);
  } else if (bid < 2560) {                // pack mask
    const int nwords = BATCH * SEQ * (SEQ / 64);  // 131072
    int wid  = (((bid - 2048) << 8) + t) >> 6;
    int lane = t & 63;
    for (int w = wid; w < nwords; w += 2048) {
      int mv = mask[(long)w * 64 + lane];
      unsigned long long bb = __ballot(mv != 0);
      if (lane == 0) pm[w] = bb;
    }
  } else {                                // biases: 4 x 1024 elems = 512 chunks
    for (int c = t; c < 512; c += 256) {
      int seg = c >> 7;                   // 128 chunks per tensor
      long i  = c & 127;
      const float* s = seg == 0 ? bq : (seg == 1 ? bk : (seg == 2 ? bv : bo));
      unsigned short* d = seg == 0 ? bqc : (seg == 1 ? bkc : (seg == 2 ? bvc : boc));
      conv8(s, d, i);
    }
  }
}

// ---------------------------------------------------------------- GEMM core
// C = (A @ W^T + bias) * cscale.  BK=64 + global_load_lds(16B), linear
// [128][64] LDS. Sync skeleton = r21-proven: stage -> s_waitcnt vmcnt(0) ->
// barrier -> compute -> barrier. Staging: instr (w,qq) covers 8 rows x 64
// cols; lane l writes LDS elems 8l..8l+7 ((l>>3)*64+(l&7)*8 == 8l: linear).
// mode 0: row-major f32.  mode 1: bf16 scatter [B,H,S,dk].
// mode 2: bf16 scatter-transposed [B,H,dk,S] with packed 8B stores.
#define BK 64

static __device__ __forceinline__ void gemm_body(const unsigned short* __restrict__ A,
                                                 const unsigned short* __restrict__ W,
                                                 const unsigned short* __restrict__ bias,
                                                 void* __restrict__ Cv,
                                                 int mode, float cscale, int bid,
                                                 unsigned short* Al, unsigned short* Bl) {
  const int t    = threadIdx.x;
  const int lane = t & 63;
  const int w    = t >> 6;
  const int wm   = w >> 1, wn = w & 1;
  const int g    = lane >> 4, lr = lane & 15;
  const int nb   = bid & 7;
  const int mb   = bid >> 3;
  const long Abase = (long)mb * 128 * 1024;
  const long Wbase = (long)nb * 128 * 1024;
  const int srow = lane >> 3;          // 0..7 within 8-row slab
  const int scol = (lane & 7) << 3;    // 0..56

  f32x4 acc[4][4] = {};

  for (int kt = 0; kt < 1024; kt += BK) {
    __syncthreads();                   // previous tile's reads complete
#pragma unroll
    for (int qq = 0; qq < 4; ++qq) {
      int slab = w * 4 + qq;           // 0..15, 8 rows each
      int row  = slab * 8 + srow;
      gl_lds16(A + Abase + (long)row * 1024 + kt + scol, Al + slab * 512);
      gl_lds16(W + Wbase + (long)row * 1024 + kt + scol, Bl + slab * 512);
    }
    // drain this wave's direct-to-LDS loads before the barrier (r21-proven)
    asm volatile("s_waitcnt vmcnt(0)" ::: "memory");
    __syncthreads();                   // tile resident for all waves
#pragma unroll
    for (int kh = 0; kh < 2; ++kh) {
      bf16x8 af[4], bfr[4];
#pragma unroll
      for (int i = 0; i < 4; ++i) {
        af[i]  = *(const bf16x8*)(&Al[(wm * 64 + i * 16 + lr) * 64 + kh * 32 + g * 8]);
        bfr[i] = *(const bf16x8*)(&Bl[(wn * 64 + i * 16 + lr) * 64 + kh * 32 + g * 8]);
      }
#pragma unroll
      for (int i = 0; i < 4; ++i)
#pragma unroll
        for (int j = 0; j < 4; ++j)
          acc[i][j] = __builtin_amdgcn_mfma_f32_16x16x32_bf16(af[i], bfr[j], acc[i][j], 0, 0, 0);
    }
  }

#pragma unroll
  for (int j = 0; j < 4; ++j) {
    int n = nb * 128 + wn * 64 + j * 16 + lr;
    float bv = bf2f(bias[n]);
#pragma unroll
    for (int i = 0; i < 4; ++i) {
      int m0 = mb * 128 + wm * 64 + i * 16 + g * 4;
      float v0 = (acc[i][j][0] + bv) * cscale;
      float v1 = (acc[i][j][1] + bv) * cscale;
      float v2 = (acc[i][j][2] + bv) * cscale;
      float v3 = (acc[i][j][3] + bv) * cscale;
      if (mode == 2) {            // V^T: [B,H,dk,S]; 4 consecutive s -> 8B store
        int b = m0 >> 11, s0 = m0 & (SEQ - 1);
        int h = n >> 6, d = n & (DK - 1);
        uint2 pk;
        pk.x = (unsigned)f2bf(v0) | ((unsigned)f2bf(v1) << 16);
        pk.y = (unsigned)f2bf(v2) | ((unsigned)f2bf(v3) << 16);
        *(uint2*)(&((unsigned short*)Cv)[((long)(b * NH + h) * DK + d) * SEQ + s0]) = pk;
      } else if (mode == 1) {     // [B,H,S,dk]
        int b = m0 >> 11, s0 = m0 & (SEQ - 1);
        int h = n >> 6, d = n & (DK - 1);
        unsigned short* p = &((unsigned short*)Cv)[(((long)(b * NH + h) * SEQ + s0) << 6) + d];
        p[0] = f2bf(v0); p[64] = f2bf(v1); p[128] = f2bf(v2); p[192] = f2bf(v3);
      } else {                    // row-major f32
        float* p = &((float*)Cv)[(long)m0 * DMODEL + n];
        p[0] = v0; p[DMODEL] = v1; p[2 * DMODEL] = v2; p[3 * DMODEL] = v3;
      }
    }
  }
}

// merged Q/K/V projection: 768 blocks, which = blockIdx.x >> 8
__global__ __launch_bounds__(256) void qkv_proj(const unsigned short* __restrict__ Aq,
                                                const unsigned short* __restrict__ Ak,
                                                const unsigned short* __restrict__ Av,
                                                const unsigned short* __restrict__ Wq,
                                                const unsigned short* __restrict__ Wk,
                                                const unsigned short* __restrict__ Wv,
                                                const unsigned short* __restrict__ bq,
                                                const unsigned short* __restrict__ bk,
                                                const unsigned short* __restrict__ bv,
                                                unsigned short* __restrict__ Cq,
                                                unsigned short* __restrict__ Ck,
                                                unsigned short* __restrict__ Cv) {
  __shared__ unsigned short Al[128 * 64];
  __shared__ unsigned short Bl[128 * 64];
  int which = blockIdx.x >> 8;
  int bid   = blockIdx.x & 255;
  const unsigned short* A = which == 0 ? Aq : (which == 1 ? Ak : Av);
  const unsigned short* W = which == 0 ? Wq : (which == 1 ? Wk : Wv);
  const unsigned short* b = which == 0 ? bq : (which == 1 ? bk : bv);
  unsigned short* C = which == 0 ? Cq : (which == 1 ? Ck : Cv);
  int   mode  = which == 2 ? 2 : 1;
  float scale = which == 0 ? QSCALE : 1.0f;
  gemm_body(A, W, b, C, mode, scale, bid, Al, Bl);
}

__global__ __launch_bounds__(256) void gemm_out(const unsigned short* __restrict__ A,
                                                const unsigned short* __restrict__ W,
                                                const unsigned short* __restrict__ bias,
                                                float* __restrict__ C) {
  __shared__ unsigned short Al[128 * 64];
  __shared__ unsigned short Bl[128 * 64];
  gemm_body(A, W, bias, C, 0, 1.0f, blockIdx.x, Al, Bl);
}

// ---------------------------------------------------------------- attention
// EXACT r20/r21 attn (validated both checks): XCD swizzle + wave-private P
// fences + register-prefetch staging.
#define KVB 64
#define LD 72

__global__ __launch_bounds__(256) void attn(const unsigned short* __restrict__ Q,
                                            const unsigned short* __restrict__ K,
                                            const unsigned short* __restrict__ VT,
                                            const unsigned long long* __restrict__ pm,
                                            unsigned short* __restrict__ O) {
  __shared__ unsigned short Kl[KVB * LD];
  __shared__ unsigned short Vt[DK * LD];       // Vt[d][kv]
  __shared__ unsigned short Pl[4][32 * LD];    // per-wave 32 q-rows (private)
  const int t    = threadIdx.x;
  const int lane = t & 63;
  const int w    = t >> 6;
  const int g    = lane >> 4, lr = lane & 15;
  const int bh   = blockIdx.x & 31;            // XCD swizzle: bh = id % 32
  const int qb   = blockIdx.x >> 5;            // 0..15
  const int b    = bh >> 4, h = bh & 15;
  const long base = (long)bh * SEQ * DK;       // same flat size for K and VT
  const int q0   = qb * 128 + w * 32;          // wave's first q-row

  // staging geometry (per thread, 2 chunks each for K and V^T)
  const int kr0 = t >> 3,         kc0 = (t & 7) << 3;
  const int kr1 = (256 + t) >> 3, kc1 = kc0;   // rows 32..63 / d 32..63

  // Q fragments: qf[qh][kh] (B-operand of swapped QK^T)
  bf16x8 qf[2][2];
#pragma unroll
  for (int qh = 0; qh < 2; ++qh) {
    const unsigned short* qp = Q + base + (long)(q0 + qh * 16 + lr) * DK;
    qf[qh][0] = *(const bf16x8*)(qp + g * 8);
    qf[qh][1] = *(const bf16x8*)(qp + 32 + g * 8);
  }
  float mrun[2] = {NEGI, NEGI}, lrun[2] = {0.f, 0.f};  // log2-domain
  f32x4 o[2][4] = {};

  // prefetch tile 0 into registers
  bf16x8 kreg0 = *(const bf16x8*)(K + base + (long)kr0 * DK + kc0);
  bf16x8 kreg1 = *(const bf16x8*)(K + base + (long)kr1 * DK + kc1);
  bf16x8 vreg0 = *(const bf16x8*)(VT + base + (long)kr0 * SEQ + kc0);
  bf16x8 vreg1 = *(const bf16x8*)(VT + base + (long)kr1 * SEQ + kc1);

  for (int kt = 0; kt < SEQ / KVB; ++kt) {
    __syncthreads();   // all reads of the previous tile done; LDS reusable
    *(bf16x8*)(&Kl[kr0 * LD + kc0]) = kreg0;
    *(bf16x8*)(&Kl[kr1 * LD + kc1]) = kreg1;
    *(bf16x8*)(&Vt[kr0 * LD + kc0]) = vreg0;
    *(bf16x8*)(&Vt[kr1 * LD + kc1]) = vreg1;
    if (kt + 1 < SEQ / KVB) {     // issue next tile's loads; latency hides
      const int kvb = (kt + 1) * KVB;
      kreg0 = *(const bf16x8*)(K + base + (long)(kvb + kr0) * DK + kc0);
      kreg1 = *(const bf16x8*)(K + base + (long)(kvb + kr1) * DK + kc1);
      vreg0 = *(const bf16x8*)(VT + base + (long)kr0 * SEQ + kvb + kc0);
      vreg1 = *(const bf16x8*)(VT + base + (long)kr1 * SEQ + kvb + kc1);
    }
    __syncthreads();   // tile kt resident in LDS

    // swapped scores: C[kv][q] for both q-groups; K frags read ONCE
    f32x4 sc[2][4];
#pragma unroll
    for (int c = 0; c < 4; ++c) {
      bf16x8 kf0 = *(const bf16x8*)(&Kl[(c * 16 + lr) * LD + g * 8]);
      bf16x8 kf1 = *(const bf16x8*)(&Kl[(c * 16 + lr) * LD + 32 + g * 8]);
#pragma unroll
      for (int qh = 0; qh < 2; ++qh) {
        f32x4 a = {};
        a = __builtin_amdgcn_mfma_f32_16x16x32_bf16(kf0, qf[qh][0], a, 0, 0, 0);
        a = __builtin_amdgcn_mfma_f32_16x16x32_bf16(kf1, qf[qh][1], a, 0, 0, 0);
        sc[qh][c] = a;
      }
    }

    unsigned short* P = &Pl[w][0];
#pragma unroll
    for (int qh = 0; qh < 2; ++qh) {
      const unsigned long long mw = pm[((long)b * SEQ + q0 + qh * 16 + lr) * 32 + kt];
      float s[4][4];
      float mt = NEGI;
#pragma unroll
      for (int c = 0; c < 4; ++c)
#pragma unroll
        for (int r = 0; r < 4; ++r) {
          int kvi = c * 16 + g * 4 + r;
          float v = ((mw >> kvi) & 1ull) ? sc[qh][c][r] : -1e9f;
          s[c][r] = v;
          mt = fmaxf(mt, v);
        }
      mt = fmaxf(mt, __shfl_xor(mt, 16, 64));
      mt = fmaxf(mt, __shfl_xor(mt, 32, 64));

      int need = __any(mt > mrun[qh] + 5.0f);   // defer-max (T13), log2 units
      float mn = mrun[qh], corr = 1.0f;
      if (need) { mn = fmaxf(mrun[qh], mt); corr = __builtin_amdgcn_exp2f(mrun[qh] - mn); mrun[qh] = mn; }

      float pf[4][4];
      float rs = 0.f;
#pragma unroll
      for (int c = 0; c < 4; ++c)
#pragma unroll
        for (int r = 0; r < 4; ++r) {
          float p_ = __builtin_amdgcn_exp2f(s[c][r] - mn);
          pf[c][r] = p_;
          rs += p_;
        }
      rs += __shfl_xor(rs, 16, 64);
      rs += __shfl_xor(rs, 32, 64);

      if (need) {
        lrun[qh] = lrun[qh] * corr + rs;
#pragma unroll
        for (int r = 0; r < 4; ++r) {
          float cq = __shfl(corr, (lane >> 4) * 4 + r, 64);  // corr of q-row g*4+r
#pragma unroll
          for (int dt = 0; dt < 4; ++dt) o[qh][dt][r] *= cq;
        }
      } else {
        lrun[qh] += rs;
      }

      // P store (A-fragment layout): row q-local = qh*16+lr, kv cols
#pragma unroll
      for (int c = 0; c < 4; ++c) {
        uint2 pk;
        pk.x = cvtpk(pf[c][0], pf[c][1]);
        pk.y = cvtpk(pf[c][2], pf[c][3]);
        *(uint2*)(&P[(qh * 16 + lr) * LD + c * 16 + g * 4]) = pk;
      }
    }
    // within-wave fence (Pl[w] is wave-private): P ds_writes drained, and no
    // hoisting of the PV ds_reads above this point (r15/r18/r19-validated).
    asm volatile("s_waitcnt lgkmcnt(0)" ::: "memory");
    __builtin_amdgcn_sched_barrier(0);

    // PV: V fragments read ONCE, used by both q-groups
#pragma unroll
    for (int c32 = 0; c32 < 2; ++c32) {
      bf16x8 pf0 = *(const bf16x8*)(&P[lr * LD + c32 * 32 + g * 8]);
      bf16x8 pf1 = *(const bf16x8*)(&P[(16 + lr) * LD + c32 * 32 + g * 8]);
#pragma unroll
      for (int dt = 0; dt < 4; ++dt) {
        bf16x8 vf = *(const bf16x8*)(&Vt[(dt * 16 + lr) * LD + c32 * 32 + g * 8]);
        o[0][dt] = __builtin_amdgcn_mfma_f32_16x16x32_bf16(pf0, vf, o[0][dt], 0, 0, 0);
        o[1][dt] = __builtin_amdgcn_mfma_f32_16x16x32_bf16(pf1, vf, o[1][dt], 0, 0, 0);
      }
    }
    // drain the PV ds_reads of P before the next tile's P ds_writes
    asm volatile("s_waitcnt lgkmcnt(0)" ::: "memory");
    __builtin_amdgcn_sched_barrier(0);
  }
#pragma unroll
  for (int qh = 0; qh < 2; ++qh) {
    float inv = 1.0f / lrun[qh];
#pragma unroll
    for (int r = 0; r < 4; ++r) {
      float iq = __shfl(inv, (lane >> 4) * 4 + r, 64);
      int q = q0 + qh * 16 + g * 4 + r;
      unsigned short* op = O + ((long)(b * SEQ + q) * DMODEL) + h * DK;
#pragma unroll
      for (int dt = 0; dt < 4; ++dt) op[dt * 16 + lr] = f2bf(o[qh][dt][r] * iq);
    }
  }
}

// ---------------------------------------------------------------- launch
extern "C" void kernel_launch(void* const* d_in, const int* in_sizes, int n_in,
                              void* d_out, int out_size, void* d_ws, size_t ws_size,
                              hipStream_t stream) {
  const int* maskp = (const int*)d_in[3];
  float* out = (float*)d_out;

  char* ws = (char*)d_ws;
  const long MB = 1 << 20;
  unsigned long long* pm = (unsigned long long*)ws;             // 1 MB
  unsigned short* Qc  = (unsigned short*)(ws + 1 * MB);         // 8 MB each
  unsigned short* Kc  = (unsigned short*)(ws + 9 * MB);
  unsigned short* Vc  = (unsigned short*)(ws + 17 * MB);
  unsigned short* Wqc = (unsigned short*)(ws + 25 * MB);        // 2 MB each
  unsigned short* Wkc = (unsigned short*)(ws + 27 * MB);
  unsigned short* Wvc = (unsigned short*)(ws + 29 * MB);
  unsigned short* Woc = (unsigned short*)(ws + 31 * MB);
  unsigned short* bqc = (unsigned short*)(ws + 33 * MB);        // 2 KB each
  unsigned short* bkc = (unsigned short*)(ws + 33 * MB + 4096);
  unsigned short* bvc = (unsigned short*)(ws + 33 * MB + 8192);
  unsigned short* boc = (unsigned short*)(ws + 33 * MB + 12288);
  unsigned short* Qb  = (unsigned short*)(ws + 35 * MB);        // 8 MB each
  unsigned short* Kb  = (unsigned short*)(ws + 43 * MB);
  unsigned short* Vb  = (unsigned short*)(ws + 51 * MB);        // holds V^T
  unsigned short* Ab  = (unsigned short*)(ws + 59 * MB);

  prep<<<2561, 256, 0, stream>>>((const float*)d_in[0], (const float*)d_in[1],
                                 (const float*)d_in[2],
                                 (const float*)d_in[4], (const float*)d_in[6],
                                 (const float*)d_in[8], (const float*)d_in[10],
                                 (const float*)d_in[5], (const float*)d_in[7],
                                 (const float*)d_in[9], (const float*)d_in[11],
                                 maskp,
                                 Qc, Kc, Vc, Wqc, Wkc, Wvc, Woc,
                                 bqc, bkc, bvc, boc, pm);

  qkv_proj<<<768, 256, 0, stream>>>(Qc, Kc, Vc, Wqc, Wkc, Wvc,
                                    bqc, bkc, bvc, Qb, Kb, Vb);

  attn<<<BATCH * NH * (SEQ / 128), 256, 0, stream>>>(Qb, Kb, Vb, pm, Ab);

  gemm_out<<<256, 256, 0, stream>>>(Ab, Woc, boc, out);
}

// Round 23
// 182.749 us; speedup vs baseline: 1.0450x; 1.0450x over previous
//
#include <hip/hip_runtime.h>
#include <hip/hip_bf16.h>

#define NH 16
#define DK 64
#define SEQ 2048
#define DMODEL 1024
#define BATCH 2
#define MROWS (BATCH * SEQ) /* 4096 */

using bf16x8 = __attribute__((ext_vector_type(8))) short;
using f32x4  = __attribute__((ext_vector_type(4))) float;

#define NEGI (-1e30f)
#define QSCALE 0.18033688f  /* 0.125 * log2(e): folds 1/sqrt(dk) and exp->exp2 */

static __device__ __forceinline__ unsigned short f2bf(float x) {
  unsigned u = __builtin_bit_cast(unsigned, x);
  u += 0x7fffu + ((u >> 16) & 1u);   // RNE
  return (unsigned short)(u >> 16);
}
static __device__ __forceinline__ float bf2f(unsigned short h) {
  unsigned u = ((unsigned)h) << 16;
  return __builtin_bit_cast(float, u);
}
// packed f32x2 -> bf16x2 (lo = a, hi = b), single VALU inst
static __device__ __forceinline__ unsigned cvtpk(float a, float b) {
  unsigned r;
  asm("v_cvt_pk_bf16_f32 %0, %1, %2" : "=v"(r) : "v"(a), "v"(b));
  return r;
}
// async global->LDS, 16B per lane; LDS dest is wave-uniform base + lane*16
static __device__ __forceinline__ void gl_lds16(const unsigned short* g,
                                                unsigned short* l) {
  __builtin_amdgcn_global_load_lds(
      (const __attribute__((address_space(1))) unsigned int*)g,
      (__attribute__((address_space(3))) unsigned int*)l, 16, 0, 0);
}

// ------------------------------------------------- converts (f32 -> bf16)
__global__ __launch_bounds__(256) void convert3(const float* __restrict__ s0,
                                                const float* __restrict__ s1,
                                                const float* __restrict__ s2,
                                                unsigned short* __restrict__ d0,
                                                unsigned short* __restrict__ d1,
                                                unsigned short* __restrict__ d2,
                                                long n8, int blkseg) {
  int seg = blockIdx.x / blkseg;
  int ib  = blockIdx.x % blkseg;
  const float* s = seg == 0 ? s0 : (seg == 1 ? s1 : s2);
  unsigned short* d = seg == 0 ? d0 : (seg == 1 ? d1 : d2);
  long i0 = (long)ib * blockDim.x + threadIdx.x;
  long stride = (long)blkseg * blockDim.x;
  for (long i = i0; i < n8; i += stride) {
    const float* p = s + i * 8;
    float4 a = *(const float4*)(p);
    float4 b = *(const float4*)(p + 4);
    uint4 u = {cvtpk(a.x, a.y), cvtpk(a.z, a.w), cvtpk(b.x, b.y), cvtpk(b.z, b.w)};
    *(bf16x8*)(d + i * 8) = __builtin_bit_cast(bf16x8, u);
  }
}
__global__ __launch_bounds__(256) void convert4(const float* __restrict__ s0,
                                                const float* __restrict__ s1,
                                                const float* __restrict__ s2,
                                                const float* __restrict__ s3,
                                                unsigned short* __restrict__ d0,
                                                unsigned short* __restrict__ d1,
                                                unsigned short* __restrict__ d2,
                                                unsigned short* __restrict__ d3,
                                                long n8, int blkseg) {
  int seg = blockIdx.x / blkseg;
  int ib  = blockIdx.x % blkseg;
  const float* s = seg == 0 ? s0 : (seg == 1 ? s1 : (seg == 2 ? s2 : s3));
  unsigned short* d = seg == 0 ? d0 : (seg == 1 ? d1 : (seg == 2 ? d2 : d3));
  long i0 = (long)ib * blockDim.x + threadIdx.x;
  long stride = (long)blkseg * blockDim.x;
  for (long i = i0; i < n8; i += stride) {
    const float* p = s + i * 8;
    float4 a = *(const float4*)(p);
    float4 b = *(const float4*)(p + 4);
    uint4 u = {cvtpk(a.x, a.y), cvtpk(a.z, a.w), cvtpk(b.x, b.y), cvtpk(b.z, b.w)};
    *(bf16x8*)(d + i * 8) = __builtin_bit_cast(bf16x8, u);
  }
}

// ---------------------------------------------------------------- pack mask
__global__ __launch_bounds__(256) void pack_mask(const int* __restrict__ mask,
                                                 unsigned long long* __restrict__ pm,
                                                 int nwords) {
  int wid  = (blockIdx.x * blockDim.x + threadIdx.x) >> 6;
  int lane = threadIdx.x & 63;
  int nw   = (gridDim.x * blockDim.x) >> 6;
  for (int w = wid; w < nwords; w += nw) {
    int v = mask[(long)w * 64 + lane];
    unsigned long long b = __ballot(v != 0);
    if (lane == 0) pm[w] = b;
  }
}

// ---------------------------------------------------------------- GEMM core
// C = (A @ W^T + bias) * cscale.  m97 structure: BK=32, linear [128][32] LDS,
// global_load_lds(16B) staging, explicit s_waitcnt vmcnt(0) before the
// post-staging barrier (replay-race fix, r21-proven).
// mode 0: row-major f32.  mode 1: bf16 scatter [B,H,S,dk].
// mode 2: bf16 scatter-transposed [B,H,dk,S] with packed 8B stores.
#define BK 32

static __device__ __forceinline__ void gemm_body(const unsigned short* __restrict__ A,
                                                 const unsigned short* __restrict__ W,
                                                 const unsigned short* __restrict__ bias,
                                                 void* __restrict__ Cv,
                                                 int mode, float cscale, int bid,
                                                 unsigned short* Al, unsigned short* Bl) {
  const int t    = threadIdx.x;
  const int lane = t & 63;
  const int w    = t >> 6;
  const int wm   = w >> 1, wn = w & 1;
  const int g    = lane >> 4, lr = lane & 15;
  const int nb   = bid & 7;
  const int mb   = bid >> 3;
  const long Abase = (long)mb * 128 * 1024;
  const long Wbase = (long)nb * 128 * 1024;
  // staging geometry: slab = w*2+q covers 16 rows of 32 elems (1 KB linear)
  const int srow = lane >> 2;          // 0..15 within slab
  const int scol = (lane & 3) << 3;    // 0,8,16,24

  f32x4 acc[4][4] = {};

  for (int kt = 0; kt < 1024; kt += BK) {
    __syncthreads();                   // previous tile's reads complete
#pragma unroll
    for (int q = 0; q < 2; ++q) {
      int slab = w * 2 + q;            // 0..7
      int row  = slab * 16 + srow;
      gl_lds16(A + Abase + (long)row * 1024 + kt + scol, Al + slab * 512);
      gl_lds16(W + Wbase + (long)row * 1024 + kt + scol, Bl + slab * 512);
    }
    // drain this wave's direct-to-LDS loads before the barrier (race fix)
    asm volatile("s_waitcnt vmcnt(0)" ::: "memory");
    __syncthreads();                   // tile resident for all waves
    bf16x8 af[4], bfr[4];
#pragma unroll
    for (int i = 0; i < 4; ++i) {
      af[i]  = *(const bf16x8*)(&Al[(wm * 64 + i * 16 + lr) * 32 + g * 8]);
      bfr[i] = *(const bf16x8*)(&Bl[(wn * 64 + i * 16 + lr) * 32 + g * 8]);
    }
#pragma unroll
    for (int i = 0; i < 4; ++i)
#pragma unroll
      for (int j = 0; j < 4; ++j)
        acc[i][j] = __builtin_amdgcn_mfma_f32_16x16x32_bf16(af[i], bfr[j], acc[i][j], 0, 0, 0);
  }

#pragma unroll
  for (int j = 0; j < 4; ++j) {
    int n = nb * 128 + wn * 64 + j * 16 + lr;
    float bv = bf2f(bias[n]);
#pragma unroll
    for (int i = 0; i < 4; ++i) {
      int m0 = mb * 128 + wm * 64 + i * 16 + g * 4;
      float v0 = (acc[i][j][0] + bv) * cscale;
      float v1 = (acc[i][j][1] + bv) * cscale;
      float v2 = (acc[i][j][2] + bv) * cscale;
      float v3 = (acc[i][j][3] + bv) * cscale;
      if (mode == 2) {            // V^T: [B,H,dk,S]; 4 consecutive s -> 8B store
        int b = m0 >> 11, s0 = m0 & (SEQ - 1);
        int h = n >> 6, d = n & (DK - 1);
        uint2 pk;
        pk.x = (unsigned)f2bf(v0) | ((unsigned)f2bf(v1) << 16);
        pk.y = (unsigned)f2bf(v2) | ((unsigned)f2bf(v3) << 16);
        *(uint2*)(&((unsigned short*)Cv)[((long)(b * NH + h) * DK + d) * SEQ + s0]) = pk;
      } else if (mode == 1) {     // [B,H,S,dk]
        int b = m0 >> 11, s0 = m0 & (SEQ - 1);
        int h = n >> 6, d = n & (DK - 1);
        unsigned short* p = &((unsigned short*)Cv)[(((long)(b * NH + h) * SEQ + s0) << 6) + d];
        p[0] = f2bf(v0); p[64] = f2bf(v1); p[128] = f2bf(v2); p[192] = f2bf(v3);
      } else {                    // row-major f32
        float* p = &((float*)Cv)[(long)m0 * DMODEL + n];
        p[0] = v0; p[DMODEL] = v1; p[2 * DMODEL] = v2; p[3 * DMODEL] = v3;
      }
    }
  }
}

// merged Q/K/V projection: 768 blocks, which = blockIdx.x >> 8
__global__ __launch_bounds__(256) void qkv_proj(const unsigned short* __restrict__ Aq,
                                                const unsigned short* __restrict__ Ak,
                                                const unsigned short* __restrict__ Av,
                                                const unsigned short* __restrict__ Wq,
                                                const unsigned short* __restrict__ Wk,
                                                const unsigned short* __restrict__ Wv,
                                                const unsigned short* __restrict__ bq,
                                                const unsigned short* __restrict__ bk,
                                                const unsigned short* __restrict__ bv,
                                                unsigned short* __restrict__ Cq,
                                                unsigned short* __restrict__ Ck,
                                                unsigned short* __restrict__ Cv) {
  __shared__ unsigned short Al[128 * 32];
  __shared__ unsigned short Bl[128 * 32];
  int which = blockIdx.x >> 8;
  int bid   = blockIdx.x & 255;
  const unsigned short* A = which == 0 ? Aq : (which == 1 ? Ak : Av);
  const unsigned short* W = which == 0 ? Wq : (which == 1 ? Wk : Wv);
  const unsigned short* b = which == 0 ? bq : (which == 1 ? bk : bv);
  unsigned short* C = which == 0 ? Cq : (which == 1 ? Ck : Cv);
  int   mode  = which == 2 ? 2 : 1;
  float scale = which == 0 ? QSCALE : 1.0f;
  gemm_body(A, W, b, C, mode, scale, bid, Al, Bl);
}

__global__ __launch_bounds__(256) void gemm_out(const unsigned short* __restrict__ A,
                                                const unsigned short* __restrict__ W,
                                                const unsigned short* __restrict__ bias,
                                                float* __restrict__ C) {
  __shared__ unsigned short Al[128 * 32];
  __shared__ unsigned short Bl[128 * 32];
  gemm_body(A, W, bias, C, 0, 1.0f, blockIdx.x, Al, Bl);
}

// ---------------------------------------------------------------- attention
// r20/r21 attn (validated both checks, multiple rounds): XCD swizzle +
// wave-private P fences + register-prefetch staging.
#define KVB 64
#define LD 72

__global__ __launch_bounds__(256) void attn(const unsigned short* __restrict__ Q,
                                            const unsigned short* __restrict__ K,
                                            const unsigned short* __restrict__ VT,
                                            const unsigned long long* __restrict__ pm,
                                            unsigned short* __restrict__ O) {
  __shared__ unsigned short Kl[KVB * LD];
  __shared__ unsigned short Vt[DK * LD];       // Vt[d][kv]
  __shared__ unsigned short Pl[4][32 * LD];    // per-wave 32 q-rows (private)
  const int t    = threadIdx.x;
  const int lane = t & 63;
  const int w    = t >> 6;
  const int g    = lane >> 4, lr = lane & 15;
  const int bh   = blockIdx.x & 31;            // XCD swizzle: bh = id % 32
  const int qb   = blockIdx.x >> 5;            // 0..15
  const int b    = bh >> 4, h = bh & 15;
  const long base = (long)bh * SEQ * DK;       // same flat size for K and VT
  const int q0   = qb * 128 + w * 32;          // wave's first q-row

  // staging geometry (per thread, 2 chunks each for K and V^T)
  const int kr0 = t >> 3,         kc0 = (t & 7) << 3;
  const int kr1 = (256 + t) >> 3, kc1 = kc0;   // rows 32..63 / d 32..63

  // Q fragments: qf[qh][kh] (B-operand of swapped QK^T)
  bf16x8 qf[2][2];
#pragma unroll
  for (int qh = 0; qh < 2; ++qh) {
    const unsigned short* qp = Q + base + (long)(q0 + qh * 16 + lr) * DK;
    qf[qh][0] = *(const bf16x8*)(qp + g * 8);
    qf[qh][1] = *(const bf16x8*)(qp + 32 + g * 8);
  }
  float mrun[2] = {NEGI, NEGI}, lrun[2] = {0.f, 0.f};  // log2-domain
  f32x4 o[2][4] = {};

  // prefetch tile 0 into registers
  bf16x8 kreg0 = *(const bf16x8*)(K + base + (long)kr0 * DK + kc0);
  bf16x8 kreg1 = *(const bf16x8*)(K + base + (long)kr1 * DK + kc1);
  bf16x8 vreg0 = *(const bf16x8*)(VT + base + (long)kr0 * SEQ + kc0);
  bf16x8 vreg1 = *(const bf16x8*)(VT + base + (long)kr1 * SEQ + kc1);

  for (int kt = 0; kt < SEQ / KVB; ++kt) {
    __syncthreads();   // all reads of the previous tile done; LDS reusable
    *(bf16x8*)(&Kl[kr0 * LD + kc0]) = kreg0;
    *(bf16x8*)(&Kl[kr1 * LD + kc1]) = kreg1;
    *(bf16x8*)(&Vt[kr0 * LD + kc0]) = vreg0;
    *(bf16x8*)(&Vt[kr1 * LD + kc1]) = vreg1;
    if (kt + 1 < SEQ / KVB) {     // issue next tile's loads; latency hides
      const int kvb = (kt + 1) * KVB;
      kreg0 = *(const bf16x8*)(K + base + (long)(kvb + kr0) * DK + kc0);
      kreg1 = *(const bf16x8*)(K + base + (long)(kvb + kr1) * DK + kc1);
      vreg0 = *(const bf16x8*)(VT + base + (long)kr0 * SEQ + kvb + kc0);
      vreg1 = *(const bf16x8*)(VT + base + (long)kr1 * SEQ + kvb + kc1);
    }
    __syncthreads();   // tile kt resident in LDS

    // swapped scores: C[kv][q] for both q-groups; K frags read ONCE
    f32x4 sc[2][4];
#pragma unroll
    for (int c = 0; c < 4; ++c) {
      bf16x8 kf0 = *(const bf16x8*)(&Kl[(c * 16 + lr) * LD + g * 8]);
      bf16x8 kf1 = *(const bf16x8*)(&Kl[(c * 16 + lr) * LD + 32 + g * 8]);
#pragma unroll
      for (int qh = 0; qh < 2; ++qh) {
        f32x4 a = {};
        a = __builtin_amdgcn_mfma_f32_16x16x32_bf16(kf0, qf[qh][0], a, 0, 0, 0);
        a = __builtin_amdgcn_mfma_f32_16x16x32_bf16(kf1, qf[qh][1], a, 0, 0, 0);
        sc[qh][c] = a;
      }
    }

    unsigned short* P = &Pl[w][0];
#pragma unroll
    for (int qh = 0; qh < 2; ++qh) {
      const unsigned long long mw = pm[((long)b * SEQ + q0 + qh * 16 + lr) * 32 + kt];
      float s[4][4];
      float mt = NEGI;
#pragma unroll
      for (int c = 0; c < 4; ++c)
#pragma unroll
        for (int r = 0; r < 4; ++r) {
          int kvi = c * 16 + g * 4 + r;
          float v = ((mw >> kvi) & 1ull) ? sc[qh][c][r] : -1e9f;
          s[c][r] = v;
          mt = fmaxf(mt, v);
        }
      mt = fmaxf(mt, __shfl_xor(mt, 16, 64));
      mt = fmaxf(mt, __shfl_xor(mt, 32, 64));

      int need = __any(mt > mrun[qh] + 5.0f);   // defer-max (T13), log2 units
      float mn = mrun[qh], corr = 1.0f;
      if (need) { mn = fmaxf(mrun[qh], mt); corr = __builtin_amdgcn_exp2f(mrun[qh] - mn); mrun[qh] = mn; }

      float pf[4][4];
      float rs = 0.f;
#pragma unroll
      for (int c = 0; c < 4; ++c)
#pragma unroll
        for (int r = 0; r < 4; ++r) {
          float p_ = __builtin_amdgcn_exp2f(s[c][r] - mn);
          pf[c][r] = p_;
          rs += p_;
        }
      rs += __shfl_xor(rs, 16, 64);
      rs += __shfl_xor(rs, 32, 64);

      if (need) {
        lrun[qh] = lrun[qh] * corr + rs;
#pragma unroll
        for (int r = 0; r < 4; ++r) {
          float cq = __shfl(corr, (lane >> 4) * 4 + r, 64);  // corr of q-row g*4+r
#pragma unroll
          for (int dt = 0; dt < 4; ++dt) o[qh][dt][r] *= cq;
        }
      } else {
        lrun[qh] += rs;
      }

      // P store (A-fragment layout): row q-local = qh*16+lr, kv cols
#pragma unroll
      for (int c = 0; c < 4; ++c) {
        uint2 pk;
        pk.x = cvtpk(pf[c][0], pf[c][1]);
        pk.y = cvtpk(pf[c][2], pf[c][3]);
        *(uint2*)(&P[(qh * 16 + lr) * LD + c * 16 + g * 4]) = pk;
      }
    }
    // within-wave fence (Pl[w] is wave-private): P ds_writes drained, and no
    // hoisting of the PV ds_reads above this point (r15/r18/r19-validated).
    asm volatile("s_waitcnt lgkmcnt(0)" ::: "memory");
    __builtin_amdgcn_sched_barrier(0);

    // PV: V fragments read ONCE, used by both q-groups
#pragma unroll
    for (int c32 = 0; c32 < 2; ++c32) {
      bf16x8 pf0 = *(const bf16x8*)(&P[lr * LD + c32 * 32 + g * 8]);
      bf16x8 pf1 = *(const bf16x8*)(&P[(16 + lr) * LD + c32 * 32 + g * 8]);
#pragma unroll
      for (int dt = 0; dt < 4; ++dt) {
        bf16x8 vf = *(const bf16x8*)(&Vt[(dt * 16 + lr) * LD + c32 * 32 + g * 8]);
        o[0][dt] = __builtin_amdgcn_mfma_f32_16x16x32_bf16(pf0, vf, o[0][dt], 0, 0, 0);
        o[1][dt] = __builtin_amdgcn_mfma_f32_16x16x32_bf16(pf1, vf, o[1][dt], 0, 0, 0);
      }
    }
    // drain the PV ds_reads of P before the next tile's P ds_writes
    asm volatile("s_waitcnt lgkmcnt(0)" ::: "memory");
    __builtin_amdgcn_sched_barrier(0);
  }
#pragma unroll
  for (int qh = 0; qh < 2; ++qh) {
    float inv = 1.0f / lrun[qh];
#pragma unroll
    for (int r = 0; r < 4; ++r) {
      float iq = __shfl(inv, (lane >> 4) * 4 + r, 64);
      int q = q0 + qh * 16 + g * 4 + r;
      unsigned short* op = O + ((long)(b * SEQ + q) * DMODEL) + h * DK;
#pragma unroll
      for (int dt = 0; dt < 4; ++dt) op[dt * 16 + lr] = f2bf(o[qh][dt][r] * iq);
    }
  }
}

// ---------------------------------------------------------------- launch
extern "C" void kernel_launch(void* const* d_in, const int* in_sizes, int n_in,
                              void* d_out, int out_size, void* d_ws, size_t ws_size,
                              hipStream_t stream) {
  const int* maskp = (const int*)d_in[3];
  float* out = (float*)d_out;

  char* ws = (char*)d_ws;
  const long MB = 1 << 20;
  unsigned long long* pm = (unsigned long long*)ws;             // 1 MB
  unsigned short* Qc  = (unsigned short*)(ws + 1 * MB);         // 8 MB each
  unsigned short* Kc  = (unsigned short*)(ws + 9 * MB);
  unsigned short* Vc  = (unsigned short*)(ws + 17 * MB);
  unsigned short* Wqc = (unsigned short*)(ws + 25 * MB);        // 2 MB each
  unsigned short* Wkc = (unsigned short*)(ws + 27 * MB);
  unsigned short* Wvc = (unsigned short*)(ws + 29 * MB);
  unsigned short* Woc = (unsigned short*)(ws + 31 * MB);
  unsigned short* bqc = (unsigned short*)(ws + 33 * MB);        // 2 KB each
  unsigned short* bkc = (unsigned short*)(ws + 33 * MB + 4096);
  unsigned short* bvc = (unsigned short*)(ws + 33 * MB + 8192);
  unsigned short* boc = (unsigned short*)(ws + 33 * MB + 12288);
  unsigned short* Qb  = (unsigned short*)(ws + 35 * MB);        // 8 MB each
  unsigned short* Kb  = (unsigned short*)(ws + 43 * MB);
  unsigned short* Vb  = (unsigned short*)(ws + 51 * MB);        // holds V^T
  unsigned short* Ab  = (unsigned short*)(ws + 59 * MB);

  const long nQKV8 = (long)MROWS * DMODEL / 8;   // 524288
  const long nW8   = (long)DMODEL * DMODEL / 8;  // 131072
  convert3<<<1536, 256, 0, stream>>>((const float*)d_in[0], (const float*)d_in[1],
                                     (const float*)d_in[2], Qc, Kc, Vc, nQKV8, 512);
  convert4<<<512, 256, 0, stream>>>((const float*)d_in[4], (const float*)d_in[6],
                                    (const float*)d_in[8], (const float*)d_in[10],
                                    Wqc, Wkc, Wvc, Woc, nW8, 128);
  convert4<<<4, 256, 0, stream>>>((const float*)d_in[5], (const float*)d_in[7],
                                  (const float*)d_in[9], (const float*)d_in[11],
                                  bqc, bkc, bvc, boc, DMODEL / 8, 1);

  const int nwords = BATCH * SEQ * (SEQ / 64);  // 131072
  pack_mask<<<512, 256, 0, stream>>>(maskp, pm, nwords);

  qkv_proj<<<768, 256, 0, stream>>>(Qc, Kc, Vc, Wqc, Wkc, Wvc,
                                    bqc, bkc, bvc, Qb, Kb, Vb);

  attn<<<BATCH * NH * (SEQ / 128), 256, 0, stream>>>(Qb, Kb, Vb, pm, Ab);

  gemm_out<<<256, 256, 0, stream>>>(Ab, Woc, boc, out);
}

// Round 24
// 178.963 us; speedup vs baseline: 1.0671x; 1.0212x over previous
//
#include <hip/hip_runtime.h>
#include <hip/hip_bf16.h>

#define NH 16
#define DK 64
#define SEQ 2048
#define DMODEL 1024
#define BATCH 2
#define MROWS (BATCH * SEQ) /* 4096 */

using bf16x8 = __attribute__((ext_vector_type(8))) short;
using f32x4  = __attribute__((ext_vector_type(4))) float;

#define NEGI (-1e30f)
#define QSCALE 0.18033688f  /* 0.125 * log2(e): folds 1/sqrt(dk) and exp->exp2 */

static __device__ __forceinline__ unsigned short f2bf(float x) {
  unsigned u = __builtin_bit_cast(unsigned, x);
  u += 0x7fffu + ((u >> 16) & 1u);   // RNE
  return (unsigned short)(u >> 16);
}
static __device__ __forceinline__ float bf2f(unsigned short h) {
  unsigned u = ((unsigned)h) << 16;
  return __builtin_bit_cast(float, u);
}
// packed f32x2 -> bf16x2 (lo = a, hi = b), single VALU inst
static __device__ __forceinline__ unsigned cvtpk(float a, float b) {
  unsigned r;
  asm("v_cvt_pk_bf16_f32 %0, %1, %2" : "=v"(r) : "v"(a), "v"(b));
  return r;
}
// async global->LDS, 16B per lane; LDS dest is wave-uniform base + lane*16
static __device__ __forceinline__ void gl_lds16(const unsigned short* g,
                                                unsigned short* l) {
  __builtin_amdgcn_global_load_lds(
      (const __attribute__((address_space(1))) unsigned int*)g,
      (__attribute__((address_space(3))) unsigned int*)l, 16, 0, 0);
}

// ------------------------------------------------- converts (f32 -> bf16)
__global__ __launch_bounds__(256) void convert3(const float* __restrict__ s0,
                                                const float* __restrict__ s1,
                                                const float* __restrict__ s2,
                                                unsigned short* __restrict__ d0,
                                                unsigned short* __restrict__ d1,
                                                unsigned short* __restrict__ d2,
                                                long n8, int blkseg) {
  int seg = blockIdx.x / blkseg;
  int ib  = blockIdx.x % blkseg;
  const float* s = seg == 0 ? s0 : (seg == 1 ? s1 : s2);
  unsigned short* d = seg == 0 ? d0 : (seg == 1 ? d1 : d2);
  long i0 = (long)ib * blockDim.x + threadIdx.x;
  long stride = (long)blkseg * blockDim.x;
  for (long i = i0; i < n8; i += stride) {
    const float* p = s + i * 8;
    float4 a = *(const float4*)(p);
    float4 b = *(const float4*)(p + 4);
    uint4 u = {cvtpk(a.x, a.y), cvtpk(a.z, a.w), cvtpk(b.x, b.y), cvtpk(b.z, b.w)};
    *(bf16x8*)(d + i * 8) = __builtin_bit_cast(bf16x8, u);
  }
}
__global__ __launch_bounds__(256) void convert4(const float* __restrict__ s0,
                                                const float* __restrict__ s1,
                                                const float* __restrict__ s2,
                                                const float* __restrict__ s3,
                                                unsigned short* __restrict__ d0,
                                                unsigned short* __restrict__ d1,
                                                unsigned short* __restrict__ d2,
                                                unsigned short* __restrict__ d3,
                                                long n8, int blkseg) {
  int seg = blockIdx.x / blkseg;
  int ib  = blockIdx.x % blkseg;
  const float* s = seg == 0 ? s0 : (seg == 1 ? s1 : (seg == 2 ? s2 : s3));
  unsigned short* d = seg == 0 ? d0 : (seg == 1 ? d1 : (seg == 2 ? d2 : d3));
  long i0 = (long)ib * blockDim.x + threadIdx.x;
  long stride = (long)blkseg * blockDim.x;
  for (long i = i0; i < n8; i += stride) {
    const float* p = s + i * 8;
    float4 a = *(const float4*)(p);
    float4 b = *(const float4*)(p + 4);
    uint4 u = {cvtpk(a.x, a.y), cvtpk(a.z, a.w), cvtpk(b.x, b.y), cvtpk(b.z, b.w)};
    *(bf16x8*)(d + i * 8) = __builtin_bit_cast(bf16x8, u);
  }
}

// ---------------------------------------------------------------- pack mask
__global__ __launch_bounds__(256) void pack_mask(const int* __restrict__ mask,
                                                 unsigned long long* __restrict__ pm,
                                                 int nwords) {
  int wid  = (blockIdx.x * blockDim.x + threadIdx.x) >> 6;
  int lane = threadIdx.x & 63;
  int nw   = (gridDim.x * blockDim.x) >> 6;
  for (int w = wid; w < nwords; w += nw) {
    int v = mask[(long)w * 64 + lane];
    unsigned long long b = __ballot(v != 0);
    if (lane == 0) pm[w] = b;
  }
}

// ---------------------------------------------------------------- GEMM core
// C = (A @ W^T + bias) * cscale.  m97 structure: BK=32, linear [128][32] LDS,
// global_load_lds(16B) staging, s_waitcnt vmcnt(0) before the post-staging
// barrier (replay-race fix, r21-proven).
// XCD swizzle (r24): mb = bid & 31, nb = bid >> 5  =>  bid%8 == mb%8, so the
// 8 blocks sharing an A panel land on ONE XCD (A fetched once per L2, was 8x).
// mode 0: row-major f32.  mode 1: bf16 scatter [B,H,S,dk].
// mode 2: bf16 scatter-transposed [B,H,dk,S] with packed 8B stores.
#define BK 32

static __device__ __forceinline__ void gemm_body(const unsigned short* __restrict__ A,
                                                 const unsigned short* __restrict__ W,
                                                 const unsigned short* __restrict__ bias,
                                                 void* __restrict__ Cv,
                                                 int mode, float cscale, int bid,
                                                 unsigned short* Al, unsigned short* Bl) {
  const int t    = threadIdx.x;
  const int lane = t & 63;
  const int w    = t >> 6;
  const int wm   = w >> 1, wn = w & 1;
  const int g    = lane >> 4, lr = lane & 15;
  const int mb   = bid & 31;           // XCD-localized A panel
  const int nb   = bid >> 5;           // 0..7
  const long Abase = (long)mb * 128 * 1024;
  const long Wbase = (long)nb * 128 * 1024;
  // staging geometry: slab = w*2+q covers 16 rows of 32 elems (1 KB linear)
  const int srow = lane >> 2;          // 0..15 within slab
  const int scol = (lane & 3) << 3;    // 0,8,16,24

  f32x4 acc[4][4] = {};

  for (int kt = 0; kt < 1024; kt += BK) {
    __syncthreads();                   // previous tile's reads complete
#pragma unroll
    for (int q = 0; q < 2; ++q) {
      int slab = w * 2 + q;            // 0..7
      int row  = slab * 16 + srow;
      gl_lds16(A + Abase + (long)row * 1024 + kt + scol, Al + slab * 512);
      gl_lds16(W + Wbase + (long)row * 1024 + kt + scol, Bl + slab * 512);
    }
    // drain this wave's direct-to-LDS loads before the barrier (race fix)
    asm volatile("s_waitcnt vmcnt(0)" ::: "memory");
    __syncthreads();                   // tile resident for all waves
    bf16x8 af[4], bfr[4];
#pragma unroll
    for (int i = 0; i < 4; ++i) {
      af[i]  = *(const bf16x8*)(&Al[(wm * 64 + i * 16 + lr) * 32 + g * 8]);
      bfr[i] = *(const bf16x8*)(&Bl[(wn * 64 + i * 16 + lr) * 32 + g * 8]);
    }
#pragma unroll
    for (int i = 0; i < 4; ++i)
#pragma unroll
      for (int j = 0; j < 4; ++j)
        acc[i][j] = __builtin_amdgcn_mfma_f32_16x16x32_bf16(af[i], bfr[j], acc[i][j], 0, 0, 0);
  }

#pragma unroll
  for (int j = 0; j < 4; ++j) {
    int n = nb * 128 + wn * 64 + j * 16 + lr;
    float bv = bf2f(bias[n]);
#pragma unroll
    for (int i = 0; i < 4; ++i) {
      int m0 = mb * 128 + wm * 64 + i * 16 + g * 4;
      float v0 = (acc[i][j][0] + bv) * cscale;
      float v1 = (acc[i][j][1] + bv) * cscale;
      float v2 = (acc[i][j][2] + bv) * cscale;
      float v3 = (acc[i][j][3] + bv) * cscale;
      if (mode == 2) {            // V^T: [B,H,dk,S]; 4 consecutive s -> 8B store
        int b = m0 >> 11, s0 = m0 & (SEQ - 1);
        int h = n >> 6, d = n & (DK - 1);
        uint2 pk;
        pk.x = (unsigned)f2bf(v0) | ((unsigned)f2bf(v1) << 16);
        pk.y = (unsigned)f2bf(v2) | ((unsigned)f2bf(v3) << 16);
        *(uint2*)(&((unsigned short*)Cv)[((long)(b * NH + h) * DK + d) * SEQ + s0]) = pk;
      } else if (mode == 1) {     // [B,H,S,dk]
        int b = m0 >> 11, s0 = m0 & (SEQ - 1);
        int h = n >> 6, d = n & (DK - 1);
        unsigned short* p = &((unsigned short*)Cv)[(((long)(b * NH + h) * SEQ + s0) << 6) + d];
        p[0] = f2bf(v0); p[64] = f2bf(v1); p[128] = f2bf(v2); p[192] = f2bf(v3);
      } else {                    // row-major f32
        float* p = &((float*)Cv)[(long)m0 * DMODEL + n];
        p[0] = v0; p[DMODEL] = v1; p[2 * DMODEL] = v2; p[3 * DMODEL] = v3;
      }
    }
  }
}

// merged Q/K/V projection: 768 blocks, which = blockIdx.x >> 8
__global__ __launch_bounds__(256) void qkv_proj(const unsigned short* __restrict__ Aq,
                                                const unsigned short* __restrict__ Ak,
                                                const unsigned short* __restrict__ Av,
                                                const unsigned short* __restrict__ Wq,
                                                const unsigned short* __restrict__ Wk,
                                                const unsigned short* __restrict__ Wv,
                                                const unsigned short* __restrict__ bq,
                                                const unsigned short* __restrict__ bk,
                                                const unsigned short* __restrict__ bv,
                                                unsigned short* __restrict__ Cq,
                                                unsigned short* __restrict__ Ck,
                                                unsigned short* __restrict__ Cv) {
  __shared__ unsigned short Al[128 * 32];
  __shared__ unsigned short Bl[128 * 32];
  int which = blockIdx.x >> 8;
  int bid   = blockIdx.x & 255;
  const unsigned short* A = which == 0 ? Aq : (which == 1 ? Ak : Av);
  const unsigned short* W = which == 0 ? Wq : (which == 1 ? Wk : Wv);
  const unsigned short* b = which == 0 ? bq : (which == 1 ? bk : bv);
  unsigned short* C = which == 0 ? Cq : (which == 1 ? Ck : Cv);
  int   mode  = which == 2 ? 2 : 1;
  float scale = which == 0 ? QSCALE : 1.0f;
  gemm_body(A, W, b, C, mode, scale, bid, Al, Bl);
}

__global__ __launch_bounds__(256) void gemm_out(const unsigned short* __restrict__ A,
                                                const unsigned short* __restrict__ W,
                                                const unsigned short* __restrict__ bias,
                                                float* __restrict__ C) {
  __shared__ unsigned short Al[128 * 32];
  __shared__ unsigned short Bl[128 * 32];
  gemm_body(A, W, bias, C, 0, 1.0f, blockIdx.x, Al, Bl);
}

// ---------------------------------------------------------------- attention
// r20/r21/r23 attn (validated both checks, multiple rounds): XCD swizzle +
// wave-private P fences + register-prefetch staging.
#define KVB 64
#define LD 72

__global__ __launch_bounds__(256) void attn(const unsigned short* __restrict__ Q,
                                            const unsigned short* __restrict__ K,
                                            const unsigned short* __restrict__ VT,
                                            const unsigned long long* __restrict__ pm,
                                            unsigned short* __restrict__ O) {
  __shared__ unsigned short Kl[KVB * LD];
  __shared__ unsigned short Vt[DK * LD];       // Vt[d][kv]
  __shared__ unsigned short Pl[4][32 * LD];    // per-wave 32 q-rows (private)
  const int t    = threadIdx.x;
  const int lane = t & 63;
  const int w    = t >> 6;
  const int g    = lane >> 4, lr = lane & 15;
  const int bh   = blockIdx.x & 31;            // XCD swizzle: bh = id % 32
  const int qb   = blockIdx.x >> 5;            // 0..15
  const int b    = bh >> 4, h = bh & 15;
  const long base = (long)bh * SEQ * DK;       // same flat size for K and VT
  const int q0   = qb * 128 + w * 32;          // wave's first q-row

  // staging geometry (per thread, 2 chunks each for K and V^T)
  const int kr0 = t >> 3,         kc0 = (t & 7) << 3;
  const int kr1 = (256 + t) >> 3, kc1 = kc0;   // rows 32..63 / d 32..63

  // Q fragments: qf[qh][kh] (B-operand of swapped QK^T)
  bf16x8 qf[2][2];
#pragma unroll
  for (int qh = 0; qh < 2; ++qh) {
    const unsigned short* qp = Q + base + (long)(q0 + qh * 16 + lr) * DK;
    qf[qh][0] = *(const bf16x8*)(qp + g * 8);
    qf[qh][1] = *(const bf16x8*)(qp + 32 + g * 8);
  }
  float mrun[2] = {NEGI, NEGI}, lrun[2] = {0.f, 0.f};  // log2-domain
  f32x4 o[2][4] = {};

  // prefetch tile 0 into registers
  bf16x8 kreg0 = *(const bf16x8*)(K + base + (long)kr0 * DK + kc0);
  bf16x8 kreg1 = *(const bf16x8*)(K + base + (long)kr1 * DK + kc1);
  bf16x8 vreg0 = *(const bf16x8*)(VT + base + (long)kr0 * SEQ + kc0);
  bf16x8 vreg1 = *(const bf16x8*)(VT + base + (long)kr1 * SEQ + kc1);

  for (int kt = 0; kt < SEQ / KVB; ++kt) {
    __syncthreads();   // all reads of the previous tile done; LDS reusable
    *(bf16x8*)(&Kl[kr0 * LD + kc0]) = kreg0;
    *(bf16x8*)(&Kl[kr1 * LD + kc1]) = kreg1;
    *(bf16x8*)(&Vt[kr0 * LD + kc0]) = vreg0;
    *(bf16x8*)(&Vt[kr1 * LD + kc1]) = vreg1;
    if (kt + 1 < SEQ / KVB) {     // issue next tile's loads; latency hides
      const int kvb = (kt + 1) * KVB;
      kreg0 = *(const bf16x8*)(K + base + (long)(kvb + kr0) * DK + kc0);
      kreg1 = *(const bf16x8*)(K + base + (long)(kvb + kr1) * DK + kc1);
      vreg0 = *(const bf16x8*)(VT + base + (long)kr0 * SEQ + kvb + kc0);
      vreg1 = *(const bf16x8*)(VT + base + (long)kr1 * SEQ + kvb + kc1);
    }
    __syncthreads();   // tile kt resident in LDS

    // swapped scores: C[kv][q] for both q-groups; K frags read ONCE
    f32x4 sc[2][4];
#pragma unroll
    for (int c = 0; c < 4; ++c) {
      bf16x8 kf0 = *(const bf16x8*)(&Kl[(c * 16 + lr) * LD + g * 8]);
      bf16x8 kf1 = *(const bf16x8*)(&Kl[(c * 16 + lr) * LD + 32 + g * 8]);
#pragma unroll
      for (int qh = 0; qh < 2; ++qh) {
        f32x4 a = {};
        a = __builtin_amdgcn_mfma_f32_16x16x32_bf16(kf0, qf[qh][0], a, 0, 0, 0);
        a = __builtin_amdgcn_mfma_f32_16x16x32_bf16(kf1, qf[qh][1], a, 0, 0, 0);
        sc[qh][c] = a;
      }
    }

    unsigned short* P = &Pl[w][0];
#pragma unroll
    for (int qh = 0; qh < 2; ++qh) {
      const unsigned long long mw = pm[((long)b * SEQ + q0 + qh * 16 + lr) * 32 + kt];
      float s[4][4];
      float mt = NEGI;
#pragma unroll
      for (int c = 0; c < 4; ++c)
#pragma unroll
        for (int r = 0; r < 4; ++r) {
          int kvi = c * 16 + g * 4 + r;
          float v = ((mw >> kvi) & 1ull) ? sc[qh][c][r] : -1e9f;
          s[c][r] = v;
          mt = fmaxf(mt, v);
        }
      mt = fmaxf(mt, __shfl_xor(mt, 16, 64));
      mt = fmaxf(mt, __shfl_xor(mt, 32, 64));

      int need = __any(mt > mrun[qh] + 5.0f);   // defer-max (T13), log2 units
      float mn = mrun[qh], corr = 1.0f;
      if (need) { mn = fmaxf(mrun[qh], mt); corr = __builtin_amdgcn_exp2f(mrun[qh] - mn); mrun[qh] = mn; }

      float pf[4][4];
      float rs = 0.f;
#pragma unroll
      for (int c = 0; c < 4; ++c)
#pragma unroll
        for (int r = 0; r < 4; ++r) {
          float p_ = __builtin_amdgcn_exp2f(s[c][r] - mn);
          pf[c][r] = p_;
          rs += p_;
        }
      rs += __shfl_xor(rs, 16, 64);
      rs += __shfl_xor(rs, 32, 64);

      if (need) {
        lrun[qh] = lrun[qh] * corr + rs;
#pragma unroll
        for (int r = 0; r < 4; ++r) {
          float cq = __shfl(corr, (lane >> 4) * 4 + r, 64);  // corr of q-row g*4+r
#pragma unroll
          for (int dt = 0; dt < 4; ++dt) o[qh][dt][r] *= cq;
        }
      } else {
        lrun[qh] += rs;
      }

      // P store (A-fragment layout): row q-local = qh*16+lr, kv cols
#pragma unroll
      for (int c = 0; c < 4; ++c) {
        uint2 pk;
        pk.x = cvtpk(pf[c][0], pf[c][1]);
        pk.y = cvtpk(pf[c][2], pf[c][3]);
        *(uint2*)(&P[(qh * 16 + lr) * LD + c * 16 + g * 4]) = pk;
      }
    }
    // within-wave fence (Pl[w] is wave-private): P ds_writes drained, and no
    // hoisting of the PV ds_reads above this point (r15/r18/r19-validated).
    asm volatile("s_waitcnt lgkmcnt(0)" ::: "memory");
    __builtin_amdgcn_sched_barrier(0);

    // PV: V fragments read ONCE, used by both q-groups
#pragma unroll
    for (int c32 = 0; c32 < 2; ++c32) {
      bf16x8 pf0 = *(const bf16x8*)(&P[lr * LD + c32 * 32 + g * 8]);
      bf16x8 pf1 = *(const bf16x8*)(&P[(16 + lr) * LD + c32 * 32 + g * 8]);
#pragma unroll
      for (int dt = 0; dt < 4; ++dt) {
        bf16x8 vf = *(const bf16x8*)(&Vt[(dt * 16 + lr) * LD + c32 * 32 + g * 8]);
        o[0][dt] = __builtin_amdgcn_mfma_f32_16x16x32_bf16(pf0, vf, o[0][dt], 0, 0, 0);
        o[1][dt] = __builtin_amdgcn_mfma_f32_16x16x32_bf16(pf1, vf, o[1][dt], 0, 0, 0);
      }
    }
    // drain the PV ds_reads of P before the next tile's P ds_writes
    asm volatile("s_waitcnt lgkmcnt(0)" ::: "memory");
    __builtin_amdgcn_sched_barrier(0);
  }
#pragma unroll
  for (int qh = 0; qh < 2; ++qh) {
    float inv = 1.0f / lrun[qh];
#pragma unroll
    for (int r = 0; r < 4; ++r) {
      float iq = __shfl(inv, (lane >> 4) * 4 + r, 64);
      int q = q0 + qh * 16 + g * 4 + r;
      unsigned short* op = O + ((long)(b * SEQ + q) * DMODEL) + h * DK;
#pragma unroll
      for (int dt = 0; dt < 4; ++dt) op[dt * 16 + lr] = f2bf(o[qh][dt][r] * iq);
    }
  }
}

// ---------------------------------------------------------------- launch
extern "C" void kernel_launch(void* const* d_in, const int* in_sizes, int n_in,
                              void* d_out, int out_size, void* d_ws, size_t ws_size,
                              hipStream_t stream) {
  const int* maskp = (const int*)d_in[3];
  float* out = (float*)d_out;

  char* ws = (char*)d_ws;
  const long MB = 1 << 20;
  unsigned long long* pm = (unsigned long long*)ws;             // 1 MB
  unsigned short* Qc  = (unsigned short*)(ws + 1 * MB);         // 8 MB each
  unsigned short* Kc  = (unsigned short*)(ws + 9 * MB);
  unsigned short* Vc  = (unsigned short*)(ws + 17 * MB);
  unsigned short* Wqc = (unsigned short*)(ws + 25 * MB);        // 2 MB each
  unsigned short* Wkc = (unsigned short*)(ws + 27 * MB);
  unsigned short* Wvc = (unsigned short*)(ws + 29 * MB);
  unsigned short* Woc = (unsigned short*)(ws + 31 * MB);
  unsigned short* bqc = (unsigned short*)(ws + 33 * MB);        // 2 KB each
  unsigned short* bkc = (unsigned short*)(ws + 33 * MB + 4096);
  unsigned short* bvc = (unsigned short*)(ws + 33 * MB + 8192);
  unsigned short* boc = (unsigned short*)(ws + 33 * MB + 12288);
  unsigned short* Qb  = (unsigned short*)(ws + 35 * MB);        // 8 MB each
  unsigned short* Kb  = (unsigned short*)(ws + 43 * MB);
  unsigned short* Vb  = (unsigned short*)(ws + 51 * MB);        // holds V^T
  unsigned short* Ab  = (unsigned short*)(ws + 59 * MB);

  const long nQKV8 = (long)MROWS * DMODEL / 8;   // 524288
  const long nW8   = (long)DMODEL * DMODEL / 8;  // 131072
  convert3<<<1536, 256, 0, stream>>>((const float*)d_in[0], (const float*)d_in[1],
                                     (const float*)d_in[2], Qc, Kc, Vc, nQKV8, 512);
  convert4<<<512, 256, 0, stream>>>((const float*)d_in[4], (const float*)d_in[6],
                                    (const float*)d_in[8], (const float*)d_in[10],
                                    Wqc, Wkc, Wvc, Woc, nW8, 128);
  convert4<<<4, 256, 0, stream>>>((const float*)d_in[5], (const float*)d_in[7],
                                  (const float*)d_in[9], (const float*)d_in[11],
                                  bqc, bkc, bvc, boc, DMODEL / 8, 1);

  const int nwords = BATCH * SEQ * (SEQ / 64);  // 131072
  pack_mask<<<512, 256, 0, stream>>>(maskp, pm, nwords);

  qkv_proj<<<768, 256, 0, stream>>>(Qc, Kc, Vc, Wqc, Wkc, Wvc,
                                    bqc, bkc, bvc, Qb, Kb, Vb);

  attn<<<BATCH * NH * (SEQ / 128), 256, 0, stream>>>(Qb, Kb, Vb, pm, Ab);

  gemm_out<<<256, 256, 0, stream>>>(Ab, Woc, boc, out);
}

// Round 25
// 173.472 us; speedup vs baseline: 1.1009x; 1.0316x over previous
//
#include <hip/hip_runtime.h>
#include <hip/hip_bf16.h>

#define NH 16
#define DK 64
#define SEQ 2048
#define DMODEL 1024
#define BATCH 2
#define MROWS (BATCH * SEQ) /* 4096 */

using bf16x8 = __attribute__((ext_vector_type(8))) short;
using f32x4  = __attribute__((ext_vector_type(4))) float;

#define NEGI (-1e30f)
#define QSCALE 0.18033688f  /* 0.125 * log2(e): folds 1/sqrt(dk) and exp->exp2 */

static __device__ __forceinline__ unsigned short f2bf(float x) {
  unsigned u = __builtin_bit_cast(unsigned, x);
  u += 0x7fffu + ((u >> 16) & 1u);   // RNE
  return (unsigned short)(u >> 16);
}
static __device__ __forceinline__ float bf2f(unsigned short h) {
  unsigned u = ((unsigned)h) << 16;
  return __builtin_bit_cast(float, u);
}
// packed f32x2 -> bf16x2 (lo = a, hi = b), single VALU inst
static __device__ __forceinline__ unsigned cvtpk(float a, float b) {
  unsigned r;
  asm("v_cvt_pk_bf16_f32 %0, %1, %2" : "=v"(r) : "v"(a), "v"(b));
  return r;
}
// async global->LDS, 16B per lane; LDS dest is wave-uniform base + lane*16
static __device__ __forceinline__ void gl_lds16(const unsigned short* g,
                                                unsigned short* l) {
  __builtin_amdgcn_global_load_lds(
      (const __attribute__((address_space(1))) unsigned int*)g,
      (__attribute__((address_space(3))) unsigned int*)l, 16, 0, 0);
}

static __device__ __forceinline__ void conv8(const float* s, unsigned short* d, long i) {
  const float* p = s + i * 8;
  float4 a = *(const float4*)(p);
  float4 b = *(const float4*)(p + 4);
  uint4 u = {cvtpk(a.x, a.y), cvtpk(a.z, a.w), cvtpk(b.x, b.y), cvtpk(b.z, b.w)};
  *(bf16x8*)(d + i * 8) = __builtin_bit_cast(bf16x8, u);
}

// ---------------------------------------------------------------- prep
// One launch replacing convert3 + convert4 + convert4 + pack_mask.
// blocks [0,1536): QKV converts (512 each) | [1536,2048): W converts (128 each)
// [2048,2560): pack_mask | 2560: biases. Same per-element ops as the r24
// kernels (conv8 RNE / ballot pack) — deterministic value-path only.
__global__ __launch_bounds__(256) void prep(const float* __restrict__ q,
                                            const float* __restrict__ k,
                                            const float* __restrict__ v,
                                            const float* __restrict__ wq,
                                            const float* __restrict__ wk,
                                            const float* __restrict__ wv,
                                            const float* __restrict__ wo,
                                            const float* __restrict__ bq,
                                            const float* __restrict__ bk,
                                            const float* __restrict__ bv,
                                            const float* __restrict__ bo,
                                            const int* __restrict__ mask,
                                            unsigned short* __restrict__ Qc,
                                            unsigned short* __restrict__ Kc,
                                            unsigned short* __restrict__ Vc,
                                            unsigned short* __restrict__ Wqc,
                                            unsigned short* __restrict__ Wkc,
                                            unsigned short* __restrict__ Wvc,
                                            unsigned short* __restrict__ Woc,
                                            unsigned short* __restrict__ bqc,
                                            unsigned short* __restrict__ bkc,
                                            unsigned short* __restrict__ bvc,
                                            unsigned short* __restrict__ boc,
                                            unsigned long long* __restrict__ pm) {
  const int bid = blockIdx.x;
  const int t   = threadIdx.x;
  const long nQKV8 = (long)MROWS * DMODEL / 8;   // 524288
  const long nW8   = (long)DMODEL * DMODEL / 8;  // 131072
  if (bid < 1536) {                       // QKV converts
    int seg = bid >> 9;                   // /512
    int ib  = bid & 511;
    const float* s = seg == 0 ? q : (seg == 1 ? k : v);
    unsigned short* d = seg == 0 ? Qc : (seg == 1 ? Kc : Vc);
    long i0 = (long)ib * 256 + t;
    for (long i = i0; i < nQKV8; i += 512 * 256) conv8(s, d, i);
  } else if (bid < 2048) {                // W converts
    int seg = (bid - 1536) >> 7;          // /128
    int ib  = (bid - 1536) & 127;
    const float* s = seg == 0 ? wq : (seg == 1 ? wk : (seg == 2 ? wv : wo));
    unsigned short* d = seg == 0 ? Wqc : (seg == 1 ? Wkc : (seg == 2 ? Wvc : Woc));
    long i0 = (long)ib * 256 + t;
    for (long i = i0; i < nW8; i += 128 * 256) conv8(s, d, i);
  } else if (bid < 2560) {                // pack mask
    const int nwords = BATCH * SEQ * (SEQ / 64);  // 131072
    int wid  = (((bid - 2048) << 8) + t) >> 6;
    int lane = t & 63;
    for (int w = wid; w < nwords; w += 2048) {
      int mv = mask[(long)w * 64 + lane];
      unsigned long long bb = __ballot(mv != 0);
      if (lane == 0) pm[w] = bb;
    }
  } else {                                // biases: 4 x 1024 elems = 512 chunks
    for (int c = t; c < 512; c += 256) {
      int seg = c >> 7;                   // 128 chunks per tensor
      long i  = c & 127;
      const float* s = seg == 0 ? bq : (seg == 1 ? bk : (seg == 2 ? bv : bo));
      unsigned short* d = seg == 0 ? bqc : (seg == 1 ? bkc : (seg == 2 ? bvc : boc));
      conv8(s, d, i);
    }
  }
}

// ---------------------------------------------------------------- GEMM core
// C = (A @ W^T + bias) * cscale.  m97 structure: BK=32, linear [128][32] LDS,
// global_load_lds(16B) staging, s_waitcnt vmcnt(0) before the post-staging
// barrier (replay-race fix, r21-proven).
// XCD swizzle (r24): mb = bid & 31, nb = bid >> 5  =>  bid%8 == mb%8, so the
// 8 blocks sharing an A panel land on ONE XCD (A fetched once per L2).
// mode 0: row-major f32.  mode 1: bf16 scatter [B,H,S,dk].
// mode 2: bf16 scatter-transposed [B,H,dk,S] with packed 8B stores.
#define BK 32

static __device__ __forceinline__ void gemm_body(const unsigned short* __restrict__ A,
                                                 const unsigned short* __restrict__ W,
                                                 const unsigned short* __restrict__ bias,
                                                 void* __restrict__ Cv,
                                                 int mode, float cscale, int bid,
                                                 unsigned short* Al, unsigned short* Bl) {
  const int t    = threadIdx.x;
  const int lane = t & 63;
  const int w    = t >> 6;
  const int wm   = w >> 1, wn = w & 1;
  const int g    = lane >> 4, lr = lane & 15;
  const int mb   = bid & 31;           // XCD-localized A panel
  const int nb   = bid >> 5;           // 0..7
  const long Abase = (long)mb * 128 * 1024;
  const long Wbase = (long)nb * 128 * 1024;
  // staging geometry: slab = w*2+q covers 16 rows of 32 elems (1 KB linear)
  const int srow = lane >> 2;          // 0..15 within slab
  const int scol = (lane & 3) << 3;    // 0,8,16,24

  f32x4 acc[4][4] = {};

  for (int kt = 0; kt < 1024; kt += BK) {
    __syncthreads();                   // previous tile's reads complete
#pragma unroll
    for (int q = 0; q < 2; ++q) {
      int slab = w * 2 + q;            // 0..7
      int row  = slab * 16 + srow;
      gl_lds16(A + Abase + (long)row * 1024 + kt + scol, Al + slab * 512);
      gl_lds16(W + Wbase + (long)row * 1024 + kt + scol, Bl + slab * 512);
    }
    // drain this wave's direct-to-LDS loads before the barrier (race fix)
    asm volatile("s_waitcnt vmcnt(0)" ::: "memory");
    __syncthreads();                   // tile resident for all waves
    bf16x8 af[4], bfr[4];
#pragma unroll
    for (int i = 0; i < 4; ++i) {
      af[i]  = *(const bf16x8*)(&Al[(wm * 64 + i * 16 + lr) * 32 + g * 8]);
      bfr[i] = *(const bf16x8*)(&Bl[(wn * 64 + i * 16 + lr) * 32 + g * 8]);
    }
#pragma unroll
    for (int i = 0; i < 4; ++i)
#pragma unroll
      for (int j = 0; j < 4; ++j)
        acc[i][j] = __builtin_amdgcn_mfma_f32_16x16x32_bf16(af[i], bfr[j], acc[i][j], 0, 0, 0);
  }

#pragma unroll
  for (int j = 0; j < 4; ++j) {
    int n = nb * 128 + wn * 64 + j * 16 + lr;
    float bv = bf2f(bias[n]);
#pragma unroll
    for (int i = 0; i < 4; ++i) {
      int m0 = mb * 128 + wm * 64 + i * 16 + g * 4;
      float v0 = (acc[i][j][0] + bv) * cscale;
      float v1 = (acc[i][j][1] + bv) * cscale;
      float v2 = (acc[i][j][2] + bv) * cscale;
      float v3 = (acc[i][j][3] + bv) * cscale;
      if (mode == 2) {            // V^T: [B,H,dk,S]; 4 consecutive s -> 8B store
        int b = m0 >> 11, s0 = m0 & (SEQ - 1);
        int h = n >> 6, d = n & (DK - 1);
        uint2 pk;
        pk.x = (unsigned)f2bf(v0) | ((unsigned)f2bf(v1) << 16);
        pk.y = (unsigned)f2bf(v2) | ((unsigned)f2bf(v3) << 16);
        *(uint2*)(&((unsigned short*)Cv)[((long)(b * NH + h) * DK + d) * SEQ + s0]) = pk;
      } else if (mode == 1) {     // [B,H,S,dk]
        int b = m0 >> 11, s0 = m0 & (SEQ - 1);
        int h = n >> 6, d = n & (DK - 1);
        unsigned short* p = &((unsigned short*)Cv)[(((long)(b * NH + h) * SEQ + s0) << 6) + d];
        p[0] = f2bf(v0); p[64] = f2bf(v1); p[128] = f2bf(v2); p[192] = f2bf(v3);
      } else {                    // row-major f32
        float* p = &((float*)Cv)[(long)m0 * DMODEL + n];
        p[0] = v0; p[DMODEL] = v1; p[2 * DMODEL] = v2; p[3 * DMODEL] = v3;
      }
    }
  }
}

// merged Q/K/V projection: 768 blocks, which = blockIdx.x >> 8
__global__ __launch_bounds__(256) void qkv_proj(const unsigned short* __restrict__ Aq,
                                                const unsigned short* __restrict__ Ak,
                                                const unsigned short* __restrict__ Av,
                                                const unsigned short* __restrict__ Wq,
                                                const unsigned short* __restrict__ Wk,
                                                const unsigned short* __restrict__ Wv,
                                                const unsigned short* __restrict__ bq,
                                                const unsigned short* __restrict__ bk,
                                                const unsigned short* __restrict__ bv,
                                                unsigned short* __restrict__ Cq,
                                                unsigned short* __restrict__ Ck,
                                                unsigned short* __restrict__ Cv) {
  __shared__ unsigned short Al[128 * 32];
  __shared__ unsigned short Bl[128 * 32];
  int which = blockIdx.x >> 8;
  int bid   = blockIdx.x & 255;
  const unsigned short* A = which == 0 ? Aq : (which == 1 ? Ak : Av);
  const unsigned short* W = which == 0 ? Wq : (which == 1 ? Wk : Wv);
  const unsigned short* b = which == 0 ? bq : (which == 1 ? bk : bv);
  unsigned short* C = which == 0 ? Cq : (which == 1 ? Ck : Cv);
  int   mode  = which == 2 ? 2 : 1;
  float scale = which == 0 ? QSCALE : 1.0f;
  gemm_body(A, W, b, C, mode, scale, bid, Al, Bl);
}

__global__ __launch_bounds__(256) void gemm_out(const unsigned short* __restrict__ A,
                                                const unsigned short* __restrict__ W,
                                                const unsigned short* __restrict__ bias,
                                                float* __restrict__ C) {
  __shared__ unsigned short Al[128 * 32];
  __shared__ unsigned short Bl[128 * 32];
  gemm_body(A, W, bias, C, 0, 1.0f, blockIdx.x, Al, Bl);
}

// ---------------------------------------------------------------- attention
// r20/r21/r23/r24 attn (validated both checks, multiple rounds): XCD swizzle
// + wave-private P fences + register-prefetch staging.
#define KVB 64
#define LD 72

__global__ __launch_bounds__(256) void attn(const unsigned short* __restrict__ Q,
                                            const unsigned short* __restrict__ K,
                                            const unsigned short* __restrict__ VT,
                                            const unsigned long long* __restrict__ pm,
                                            unsigned short* __restrict__ O) {
  __shared__ unsigned short Kl[KVB * LD];
  __shared__ unsigned short Vt[DK * LD];       // Vt[d][kv]
  __shared__ unsigned short Pl[4][32 * LD];    // per-wave 32 q-rows (private)
  const int t    = threadIdx.x;
  const int lane = t & 63;
  const int w    = t >> 6;
  const int g    = lane >> 4, lr = lane & 15;
  const int bh   = blockIdx.x & 31;            // XCD swizzle: bh = id % 32
  const int qb   = blockIdx.x >> 5;            // 0..15
  const int b    = bh >> 4, h = bh & 15;
  const long base = (long)bh * SEQ * DK;       // same flat size for K and VT
  const int q0   = qb * 128 + w * 32;          // wave's first q-row

  // staging geometry (per thread, 2 chunks each for K and V^T)
  const int kr0 = t >> 3,         kc0 = (t & 7) << 3;
  const int kr1 = (256 + t) >> 3, kc1 = kc0;   // rows 32..63 / d 32..63

  // Q fragments: qf[qh][kh] (B-operand of swapped QK^T)
  bf16x8 qf[2][2];
#pragma unroll
  for (int qh = 0; qh < 2; ++qh) {
    const unsigned short* qp = Q + base + (long)(q0 + qh * 16 + lr) * DK;
    qf[qh][0] = *(const bf16x8*)(qp + g * 8);
    qf[qh][1] = *(const bf16x8*)(qp + 32 + g * 8);
  }
  float mrun[2] = {NEGI, NEGI}, lrun[2] = {0.f, 0.f};  // log2-domain
  f32x4 o[2][4] = {};

  // prefetch tile 0 into registers
  bf16x8 kreg0 = *(const bf16x8*)(K + base + (long)kr0 * DK + kc0);
  bf16x8 kreg1 = *(const bf16x8*)(K + base + (long)kr1 * DK + kc1);
  bf16x8 vreg0 = *(const bf16x8*)(VT + base + (long)kr0 * SEQ + kc0);
  bf16x8 vreg1 = *(const bf16x8*)(VT + base + (long)kr1 * SEQ + kc1);

  for (int kt = 0; kt < SEQ / KVB; ++kt) {
    __syncthreads();   // all reads of the previous tile done; LDS reusable
    *(bf16x8*)(&Kl[kr0 * LD + kc0]) = kreg0;
    *(bf16x8*)(&Kl[kr1 * LD + kc1]) = kreg1;
    *(bf16x8*)(&Vt[kr0 * LD + kc0]) = vreg0;
    *(bf16x8*)(&Vt[kr1 * LD + kc1]) = vreg1;
    if (kt + 1 < SEQ / KVB) {     // issue next tile's loads; latency hides
      const int kvb = (kt + 1) * KVB;
      kreg0 = *(const bf16x8*)(K + base + (long)(kvb + kr0) * DK + kc0);
      kreg1 = *(const bf16x8*)(K + base + (long)(kvb + kr1) * DK + kc1);
      vreg0 = *(const bf16x8*)(VT + base + (long)kr0 * SEQ + kvb + kc0);
      vreg1 = *(const bf16x8*)(VT + base + (long)kr1 * SEQ + kvb + kc1);
    }
    __syncthreads();   // tile kt resident in LDS

    // swapped scores: C[kv][q] for both q-groups; K frags read ONCE
    f32x4 sc[2][4];
#pragma unroll
    for (int c = 0; c < 4; ++c) {
      bf16x8 kf0 = *(const bf16x8*)(&Kl[(c * 16 + lr) * LD + g * 8]);
      bf16x8 kf1 = *(const bf16x8*)(&Kl[(c * 16 + lr) * LD + 32 + g * 8]);
#pragma unroll
      for (int qh = 0; qh < 2; ++qh) {
        f32x4 a = {};
        a = __builtin_amdgcn_mfma_f32_16x16x32_bf16(kf0, qf[qh][0], a, 0, 0, 0);
        a = __builtin_amdgcn_mfma_f32_16x16x32_bf16(kf1, qf[qh][1], a, 0, 0, 0);
        sc[qh][c] = a;
      }
    }

    unsigned short* P = &Pl[w][0];
#pragma unroll
    for (int qh = 0; qh < 2; ++qh) {
      const unsigned long long mw = pm[((long)b * SEQ + q0 + qh * 16 + lr) * 32 + kt];
      float s[4][4];
      float mt = NEGI;
#pragma unroll
      for (int c = 0; c < 4; ++c)
#pragma unroll
        for (int r = 0; r < 4; ++r) {
          int kvi = c * 16 + g * 4 + r;
          float v = ((mw >> kvi) & 1ull) ? sc[qh][c][r] : -1e9f;
          s[c][r] = v;
          mt = fmaxf(mt, v);
        }
      mt = fmaxf(mt, __shfl_xor(mt, 16, 64));
      mt = fmaxf(mt, __shfl_xor(mt, 32, 64));

      int need = __any(mt > mrun[qh] + 5.0f);   // defer-max (T13), log2 units
      float mn = mrun[qh], corr = 1.0f;
      if (need) { mn = fmaxf(mrun[qh], mt); corr = __builtin_amdgcn_exp2f(mrun[qh] - mn); mrun[qh] = mn; }

      float pf[4][4];
      float rs = 0.f;
#pragma unroll
      for (int c = 0; c < 4; ++c)
#pragma unroll
        for (int r = 0; r < 4; ++r) {
          float p_ = __builtin_amdgcn_exp2f(s[c][r] - mn);
          pf[c][r] = p_;
          rs += p_;
        }
      rs += __shfl_xor(rs, 16, 64);
      rs += __shfl_xor(rs, 32, 64);

      if (need) {
        lrun[qh] = lrun[qh] * corr + rs;
#pragma unroll
        for (int r = 0; r < 4; ++r) {
          float cq = __shfl(corr, (lane >> 4) * 4 + r, 64);  // corr of q-row g*4+r
#pragma unroll
          for (int dt = 0; dt < 4; ++dt) o[qh][dt][r] *= cq;
        }
      } else {
        lrun[qh] += rs;
      }

      // P store (A-fragment layout): row q-local = qh*16+lr, kv cols
#pragma unroll
      for (int c = 0; c < 4; ++c) {
        uint2 pk;
        pk.x = cvtpk(pf[c][0], pf[c][1]);
        pk.y = cvtpk(pf[c][2], pf[c][3]);
        *(uint2*)(&P[(qh * 16 + lr) * LD + c * 16 + g * 4]) = pk;
      }
    }
    // within-wave fence (Pl[w] is wave-private): P ds_writes drained, and no
    // hoisting of the PV ds_reads above this point (r15/r18/r19-validated).
    asm volatile("s_waitcnt lgkmcnt(0)" ::: "memory");
    __builtin_amdgcn_sched_barrier(0);

    // PV: V fragments read ONCE, used by both q-groups
#pragma unroll
    for (int c32 = 0; c32 < 2; ++c32) {
      bf16x8 pf0 = *(const bf16x8*)(&P[lr * LD + c32 * 32 + g * 8]);
      bf16x8 pf1 = *(const bf16x8*)(&P[(16 + lr) * LD + c32 * 32 + g * 8]);
#pragma unroll
      for (int dt = 0; dt < 4; ++dt) {
        bf16x8 vf = *(const bf16x8*)(&Vt[(dt * 16 + lr) * LD + c32 * 32 + g * 8]);
        o[0][dt] = __builtin_amdgcn_mfma_f32_16x16x32_bf16(pf0, vf, o[0][dt], 0, 0, 0);
        o[1][dt] = __builtin_amdgcn_mfma_f32_16x16x32_bf16(pf1, vf, o[1][dt], 0, 0, 0);
      }
    }
    // drain the PV ds_reads of P before the next tile's P ds_writes
    asm volatile("s_waitcnt lgkmcnt(0)" ::: "memory");
    __builtin_amdgcn_sched_barrier(0);
  }
#pragma unroll
  for (int qh = 0; qh < 2; ++qh) {
    float inv = 1.0f / lrun[qh];
#pragma unroll
    for (int r = 0; r < 4; ++r) {
      float iq = __shfl(inv, (lane >> 4) * 4 + r, 64);
      int q = q0 + qh * 16 + g * 4 + r;
      unsigned short* op = O + ((long)(b * SEQ + q) * DMODEL) + h * DK;
#pragma unroll
      for (int dt = 0; dt < 4; ++dt) op[dt * 16 + lr] = f2bf(o[qh][dt][r] * iq);
    }
  }
}

// ---------------------------------------------------------------- launch
extern "C" void kernel_launch(void* const* d_in, const int* in_sizes, int n_in,
                              void* d_out, int out_size, void* d_ws, size_t ws_size,
                              hipStream_t stream) {
  const int* maskp = (const int*)d_in[3];
  float* out = (float*)d_out;

  char* ws = (char*)d_ws;
  const long MB = 1 << 20;
  unsigned long long* pm = (unsigned long long*)ws;             // 1 MB
  unsigned short* Qc  = (unsigned short*)(ws + 1 * MB);         // 8 MB each
  unsigned short* Kc  = (unsigned short*)(ws + 9 * MB);
  unsigned short* Vc  = (unsigned short*)(ws + 17 * MB);
  unsigned short* Wqc = (unsigned short*)(ws + 25 * MB);        // 2 MB each
  unsigned short* Wkc = (unsigned short*)(ws + 27 * MB);
  unsigned short* Wvc = (unsigned short*)(ws + 29 * MB);
  unsigned short* Woc = (unsigned short*)(ws + 31 * MB);
  unsigned short* bqc = (unsigned short*)(ws + 33 * MB);        // 2 KB each
  unsigned short* bkc = (unsigned short*)(ws + 33 * MB + 4096);
  unsigned short* bvc = (unsigned short*)(ws + 33 * MB + 8192);
  unsigned short* boc = (unsigned short*)(ws + 33 * MB + 12288);
  unsigned short* Qb  = (unsigned short*)(ws + 35 * MB);        // 8 MB each
  unsigned short* Kb  = (unsigned short*)(ws + 43 * MB);
  unsigned short* Vb  = (unsigned short*)(ws + 51 * MB);        // holds V^T
  unsigned short* Ab  = (unsigned short*)(ws + 59 * MB);

  prep<<<2561, 256, 0, stream>>>((const float*)d_in[0], (const float*)d_in[1],
                                 (const float*)d_in[2],
                                 (const float*)d_in[4], (const float*)d_in[6],
                                 (const float*)d_in[8], (const float*)d_in[10],
                                 (const float*)d_in[5], (const float*)d_in[7],
                                 (const float*)d_in[9], (const float*)d_in[11],
                                 maskp,
                                 Qc, Kc, Vc, Wqc, Wkc, Wvc, Woc,
                                 bqc, bkc, bvc, boc, pm);

  qkv_proj<<<768, 256, 0, stream>>>(Qc, Kc, Vc, Wqc, Wkc, Wvc,
                                    bqc, bkc, bvc, Qb, Kb, Vb);

  attn<<<BATCH * NH * (SEQ / 128), 256, 0, stream>>>(Qb, Kb, Vb, pm, Ab);

  gemm_out<<<256, 256, 0, stream>>>(Ab, Woc, boc, out);
}

// Round 26
// 172.383 us; speedup vs baseline: 1.1079x; 1.0063x over previous
//
#include <hip/hip_runtime.h>
#include <hip/hip_bf16.h>

#define NH 16
#define DK 64
#define SEQ 2048
#define DMODEL 1024
#define BATCH 2
#define MROWS (BATCH * SEQ) /* 4096 */

using bf16x8 = __attribute__((ext_vector_type(8))) short;
using f32x4  = __attribute__((ext_vector_type(4))) float;

#define NEGI (-1e30f)
#define QSCALE 0.18033688f  /* 0.125 * log2(e): folds 1/sqrt(dk) and exp->exp2 */

static __device__ __forceinline__ unsigned short f2bf(float x) {
  unsigned u = __builtin_bit_cast(unsigned, x);
  u += 0x7fffu + ((u >> 16) & 1u);   // RNE
  return (unsigned short)(u >> 16);
}
static __device__ __forceinline__ float bf2f(unsigned short h) {
  unsigned u = ((unsigned)h) << 16;
  return __builtin_bit_cast(float, u);
}
// packed f32x2 -> bf16x2 (lo = a, hi = b), single VALU inst
static __device__ __forceinline__ unsigned cvtpk(float a, float b) {
  unsigned r;
  asm("v_cvt_pk_bf16_f32 %0, %1, %2" : "=v"(r) : "v"(a), "v"(b));
  return r;
}
// async global->LDS, 16B per lane; LDS dest is wave-uniform base + lane*16
static __device__ __forceinline__ void gl_lds16(const unsigned short* g,
                                                unsigned short* l) {
  __builtin_amdgcn_global_load_lds(
      (const __attribute__((address_space(1))) unsigned int*)g,
      (__attribute__((address_space(3))) unsigned int*)l, 16, 0, 0);
}

static __device__ __forceinline__ void conv8(const float* s, unsigned short* d, long i) {
  const float* p = s + i * 8;
  float4 a = *(const float4*)(p);
  float4 b = *(const float4*)(p + 4);
  uint4 u = {cvtpk(a.x, a.y), cvtpk(a.z, a.w), cvtpk(b.x, b.y), cvtpk(b.z, b.w)};
  *(bf16x8*)(d + i * 8) = __builtin_bit_cast(bf16x8, u);
}

// ---------------------------------------------------------------- prep
// One launch (r25-proven): converts + mask pack + biases.
__global__ __launch_bounds__(256) void prep(const float* __restrict__ q,
                                            const float* __restrict__ k,
                                            const float* __restrict__ v,
                                            const float* __restrict__ wq,
                                            const float* __restrict__ wk,
                                            const float* __restrict__ wv,
                                            const float* __restrict__ wo,
                                            const float* __restrict__ bq,
                                            const float* __restrict__ bk,
                                            const float* __restrict__ bv,
                                            const float* __restrict__ bo,
                                            const int* __restrict__ mask,
                                            unsigned short* __restrict__ Qc,
                                            unsigned short* __restrict__ Kc,
                                            unsigned short* __restrict__ Vc,
                                            unsigned short* __restrict__ Wqc,
                                            unsigned short* __restrict__ Wkc,
                                            unsigned short* __restrict__ Wvc,
                                            unsigned short* __restrict__ Woc,
                                            unsigned short* __restrict__ bqc,
                                            unsigned short* __restrict__ bkc,
                                            unsigned short* __restrict__ bvc,
                                            unsigned short* __restrict__ boc,
                                            unsigned long long* __restrict__ pm) {
  const int bid = blockIdx.x;
  const int t   = threadIdx.x;
  const long nQKV8 = (long)MROWS * DMODEL / 8;   // 524288
  const long nW8   = (long)DMODEL * DMODEL / 8;  // 131072
  if (bid < 1536) {                       // QKV converts
    int seg = bid >> 9;
    int ib  = bid & 511;
    const float* s = seg == 0 ? q : (seg == 1 ? k : v);
    unsigned short* d = seg == 0 ? Qc : (seg == 1 ? Kc : Vc);
    long i0 = (long)ib * 256 + t;
    for (long i = i0; i < nQKV8; i += 512 * 256) conv8(s, d, i);
  } else if (bid < 2048) {                // W converts
    int seg = (bid - 1536) >> 7;
    int ib  = (bid - 1536) & 127;
    const float* s = seg == 0 ? wq : (seg == 1 ? wk : (seg == 2 ? wv : wo));
    unsigned short* d = seg == 0 ? Wqc : (seg == 1 ? Wkc : (seg == 2 ? Wvc : Woc));
    long i0 = (long)ib * 256 + t;
    for (long i = i0; i < nW8; i += 128 * 256) conv8(s, d, i);
  } else if (bid < 2560) {                // pack mask
    const int nwords = BATCH * SEQ * (SEQ / 64);  // 131072
    int wid  = (((bid - 2048) << 8) + t) >> 6;
    int lane = t & 63;
    for (int w = wid; w < nwords; w += 2048) {
      int mv = mask[(long)w * 64 + lane];
      unsigned long long bb = __ballot(mv != 0);
      if (lane == 0) pm[w] = bb;
    }
  } else {                                // biases
    for (int c = t; c < 512; c += 256) {
      int seg = c >> 7;
      long i  = c & 127;
      const float* s = seg == 0 ? bq : (seg == 1 ? bk : (seg == 2 ? bv : bo));
      unsigned short* d = seg == 0 ? bqc : (seg == 1 ? bkc : (seg == 2 ? bvc : boc));
      conv8(s, d, i);
    }
  }
}

// ---------------------------------------------------------------- GEMM core
// r24/r25-proven: BK=32, linear [128][32] LDS, global_load_lds(16B),
// s_waitcnt vmcnt(0) before the post-staging barrier, XCD swizzle
// (mb = bid & 31 so same-A-panel blocks share an XCD).
#define BK 32

static __device__ __forceinline__ void gemm_body(const unsigned short* __restrict__ A,
                                                 const unsigned short* __restrict__ W,
                                                 const unsigned short* __restrict__ bias,
                                                 void* __restrict__ Cv,
                                                 int mode, float cscale, int bid,
                                                 unsigned short* Al, unsigned short* Bl) {
  const int t    = threadIdx.x;
  const int lane = t & 63;
  const int w    = t >> 6;
  const int wm   = w >> 1, wn = w & 1;
  const int g    = lane >> 4, lr = lane & 15;
  const int mb   = bid & 31;           // XCD-localized A panel
  const int nb   = bid >> 5;           // 0..7
  const long Abase = (long)mb * 128 * 1024;
  const long Wbase = (long)nb * 128 * 1024;
  const int srow = lane >> 2;          // 0..15 within slab
  const int scol = (lane & 3) << 3;    // 0,8,16,24

  f32x4 acc[4][4] = {};

  for (int kt = 0; kt < 1024; kt += BK) {
    __syncthreads();                   // previous tile's reads complete
#pragma unroll
    for (int q = 0; q < 2; ++q) {
      int slab = w * 2 + q;            // 0..7
      int row  = slab * 16 + srow;
      gl_lds16(A + Abase + (long)row * 1024 + kt + scol, Al + slab * 512);
      gl_lds16(W + Wbase + (long)row * 1024 + kt + scol, Bl + slab * 512);
    }
    // drain this wave's direct-to-LDS loads before the barrier (race fix)
    asm volatile("s_waitcnt vmcnt(0)" ::: "memory");
    __syncthreads();                   // tile resident for all waves
    bf16x8 af[4], bfr[4];
#pragma unroll
    for (int i = 0; i < 4; ++i) {
      af[i]  = *(const bf16x8*)(&Al[(wm * 64 + i * 16 + lr) * 32 + g * 8]);
      bfr[i] = *(const bf16x8*)(&Bl[(wn * 64 + i * 16 + lr) * 32 + g * 8]);
    }
#pragma unroll
    for (int i = 0; i < 4; ++i)
#pragma unroll
      for (int j = 0; j < 4; ++j)
        acc[i][j] = __builtin_amdgcn_mfma_f32_16x16x32_bf16(af[i], bfr[j], acc[i][j], 0, 0, 0);
  }

#pragma unroll
  for (int j = 0; j < 4; ++j) {
    int n = nb * 128 + wn * 64 + j * 16 + lr;
    float bv = bf2f(bias[n]);
#pragma unroll
    for (int i = 0; i < 4; ++i) {
      int m0 = mb * 128 + wm * 64 + i * 16 + g * 4;
      float v0 = (acc[i][j][0] + bv) * cscale;
      float v1 = (acc[i][j][1] + bv) * cscale;
      float v2 = (acc[i][j][2] + bv) * cscale;
      float v3 = (acc[i][j][3] + bv) * cscale;
      if (mode == 2) {            // V^T: [B,H,dk,S]; 4 consecutive s -> 8B store
        int b = m0 >> 11, s0 = m0 & (SEQ - 1);
        int h = n >> 6, d = n & (DK - 1);
        uint2 pk;
        pk.x = (unsigned)f2bf(v0) | ((unsigned)f2bf(v1) << 16);
        pk.y = (unsigned)f2bf(v2) | ((unsigned)f2bf(v3) << 16);
        *(uint2*)(&((unsigned short*)Cv)[((long)(b * NH + h) * DK + d) * SEQ + s0]) = pk;
      } else if (mode == 1) {     // [B,H,S,dk]
        int b = m0 >> 11, s0 = m0 & (SEQ - 1);
        int h = n >> 6, d = n & (DK - 1);
        unsigned short* p = &((unsigned short*)Cv)[(((long)(b * NH + h) * SEQ + s0) << 6) + d];
        p[0] = f2bf(v0); p[64] = f2bf(v1); p[128] = f2bf(v2); p[192] = f2bf(v3);
      } else {                    // row-major f32
        float* p = &((float*)Cv)[(long)m0 * DMODEL + n];
        p[0] = v0; p[DMODEL] = v1; p[2 * DMODEL] = v2; p[3 * DMODEL] = v3;
      }
    }
  }
}

// merged Q/K/V projection: 768 blocks, which = blockIdx.x >> 8
__global__ __launch_bounds__(256) void qkv_proj(const unsigned short* __restrict__ Aq,
                                                const unsigned short* __restrict__ Ak,
                                                const unsigned short* __restrict__ Av,
                                                const unsigned short* __restrict__ Wq,
                                                const unsigned short* __restrict__ Wk,
                                                const unsigned short* __restrict__ Wv,
                                                const unsigned short* __restrict__ bq,
                                                const unsigned short* __restrict__ bk,
                                                const unsigned short* __restrict__ bv,
                                                unsigned short* __restrict__ Cq,
                                                unsigned short* __restrict__ Ck,
                                                unsigned short* __restrict__ Cv) {
  __shared__ unsigned short Al[128 * 32];
  __shared__ unsigned short Bl[128 * 32];
  int which = blockIdx.x >> 8;
  int bid   = blockIdx.x & 255;
  const unsigned short* A = which == 0 ? Aq : (which == 1 ? Ak : Av);
  const unsigned short* W = which == 0 ? Wq : (which == 1 ? Wk : Wv);
  const unsigned short* b = which == 0 ? bq : (which == 1 ? bk : bv);
  unsigned short* C = which == 0 ? Cq : (which == 1 ? Ck : Cv);
  int   mode  = which == 2 ? 2 : 1;
  float scale = which == 0 ? QSCALE : 1.0f;
  gemm_body(A, W, b, C, mode, scale, bid, Al, Bl);
}

__global__ __launch_bounds__(256) void gemm_out(const unsigned short* __restrict__ A,
                                                const unsigned short* __restrict__ W,
                                                const unsigned short* __restrict__ bias,
                                                float* __restrict__ C) {
  __shared__ unsigned short Al[128 * 32];
  __shared__ unsigned short Bl[128 * 32];
  gemm_body(A, W, bias, C, 0, 1.0f, blockIdx.x, Al, Bl);
}

// ---------------------------------------------------------------- attention
// r25 attn with KVB 64 -> 128: halves barrier-pair count (32 -> 16) while
// keeping LDS-op counts per 128 kv identical (QK/softmax split per qh-group,
// kf re-read from LDS). Barrier skeleton per iteration unchanged
// (stage-bar / compute / wave-fence). XCD swizzle + reg-prefetch kept.
#define KVB 128
#define LD  72    // Kl row pitch (64 cols + pad)
#define LD2 136   // Vt / Pl row pitch (128 cols + pad)

__global__ __launch_bounds__(256) void attn(const unsigned short* __restrict__ Q,
                                            const unsigned short* __restrict__ K,
                                            const unsigned short* __restrict__ VT,
                                            const unsigned long long* __restrict__ pm,
                                            unsigned short* __restrict__ O) {
  __shared__ unsigned short Kl[KVB * LD];      // [kv 0..127][64]
  __shared__ unsigned short Vt[DK * LD2];      // [d 0..63][kv 0..127]
  __shared__ unsigned short Pl[4][32 * LD2];   // per-wave 32 q-rows (private)
  const int t    = threadIdx.x;
  const int lane = t & 63;
  const int w    = t >> 6;
  const int g    = lane >> 4, lr = lane & 15;
  const int bh   = blockIdx.x & 31;            // XCD swizzle: bh = id % 32
  const int qb   = blockIdx.x >> 5;            // 0..15
  const int b    = bh >> 4, h = bh & 15;
  const long base = (long)bh * SEQ * DK;       // same flat size for K and VT
  const int q0   = qb * 128 + w * 32;          // wave's first q-row

  // staging geometry: K = 4 chunks of 8 (rows p*32 + t>>3, col (t&7)*8);
  // Vt = 4 chunks of 8 (rows p*16 + t>>4, col (t&15)*8)
  const int krr = t >> 3, kcc = (t & 7) << 3;
  const int vrr = t >> 4, vcc = (t & 15) << 3;

  // Q fragments: qf[qh][kh] (B-operand of swapped QK^T)
  bf16x8 qf[2][2];
#pragma unroll
  for (int qh = 0; qh < 2; ++qh) {
    const unsigned short* qp = Q + base + (long)(q0 + qh * 16 + lr) * DK;
    qf[qh][0] = *(const bf16x8*)(qp + g * 8);
    qf[qh][1] = *(const bf16x8*)(qp + 32 + g * 8);
  }
  float mrun[2] = {NEGI, NEGI}, lrun[2] = {0.f, 0.f};  // log2-domain
  f32x4 o[2][4] = {};

  // prefetch tile 0 into registers
  bf16x8 kreg[4], vreg[4];
#pragma unroll
  for (int p = 0; p < 4; ++p) {
    kreg[p] = *(const bf16x8*)(K + base + (long)(p * 32 + krr) * DK + kcc);
    vreg[p] = *(const bf16x8*)(VT + base + (long)(p * 16 + vrr) * SEQ + vcc);
  }

  for (int kt = 0; kt < SEQ / KVB; ++kt) {
    __syncthreads();   // all reads of the previous tile done; LDS reusable
#pragma unroll
    for (int p = 0; p < 4; ++p) {
      *(bf16x8*)(&Kl[(p * 32 + krr) * LD + kcc]) = kreg[p];
      *(bf16x8*)(&Vt[(p * 16 + vrr) * LD2 + vcc]) = vreg[p];
    }
    if (kt + 1 < SEQ / KVB) {     // issue next tile's loads; latency hides
      const int kvb = (kt + 1) * KVB;
#pragma unroll
      for (int p = 0; p < 4; ++p) {
        kreg[p] = *(const bf16x8*)(K + base + (long)(kvb + p * 32 + krr) * DK + kcc);
        vreg[p] = *(const bf16x8*)(VT + base + (long)(p * 16 + vrr) * SEQ + kvb + vcc);
      }
    }
    __syncthreads();   // tile kt resident in LDS

    unsigned short* P = &Pl[w][0];
    // per-qh: QK (8 c-chunks) -> mask -> softmax -> P store
#pragma unroll
    for (int qh = 0; qh < 2; ++qh) {
      const long prow = ((long)b * SEQ + q0 + qh * 16 + lr) * 32;
      const unsigned long long mw0 = pm[prow + 2 * kt];
      const unsigned long long mw1 = pm[prow + 2 * kt + 1];
      float s[8][4];
      float mt = NEGI;
#pragma unroll
      for (int c = 0; c < 8; ++c) {
        bf16x8 kf0 = *(const bf16x8*)(&Kl[(c * 16 + lr) * LD + g * 8]);
        bf16x8 kf1 = *(const bf16x8*)(&Kl[(c * 16 + lr) * LD + 32 + g * 8]);
        f32x4 a = {};
        a = __builtin_amdgcn_mfma_f32_16x16x32_bf16(kf0, qf[qh][0], a, 0, 0, 0);
        a = __builtin_amdgcn_mfma_f32_16x16x32_bf16(kf1, qf[qh][1], a, 0, 0, 0);
        const unsigned long long mw = (c < 4) ? mw0 : mw1;
#pragma unroll
        for (int r = 0; r < 4; ++r) {
          int kvi = (c & 3) * 16 + g * 4 + r;   // bit within the 64-bit word
          float v = ((mw >> kvi) & 1ull) ? a[r] : -1e9f;
          s[c][r] = v;
          mt = fmaxf(mt, v);
        }
      }
      mt = fmaxf(mt, __shfl_xor(mt, 16, 64));
      mt = fmaxf(mt, __shfl_xor(mt, 32, 64));

      int need = __any(mt > mrun[qh] + 5.0f);   // defer-max (T13), log2 units
      float mn = mrun[qh], corr = 1.0f;
      if (need) { mn = fmaxf(mrun[qh], mt); corr = __builtin_amdgcn_exp2f(mrun[qh] - mn); mrun[qh] = mn; }

      float rs = 0.f;
#pragma unroll
      for (int c = 0; c < 8; ++c)
#pragma unroll
        for (int r = 0; r < 4; ++r) {
          float p_ = __builtin_amdgcn_exp2f(s[c][r] - mn);
          s[c][r] = p_;                         // reuse array (VGPR control)
          rs += p_;
        }
      rs += __shfl_xor(rs, 16, 64);
      rs += __shfl_xor(rs, 32, 64);

      if (need) {
        lrun[qh] = lrun[qh] * corr + rs;
#pragma unroll
        for (int r = 0; r < 4; ++r) {
          float cq = __shfl(corr, (lane >> 4) * 4 + r, 64);  // corr of q-row g*4+r
#pragma unroll
          for (int dt = 0; dt < 4; ++dt) o[qh][dt][r] *= cq;
        }
      } else {
        lrun[qh] += rs;
      }

      // P store (A-fragment layout): row q-local = qh*16+lr, kv cols 0..127
#pragma unroll
      for (int c = 0; c < 8; ++c) {
        uint2 pk;
        pk.x = cvtpk(s[c][0], s[c][1]);
        pk.y = cvtpk(s[c][2], s[c][3]);
        *(uint2*)(&P[(qh * 16 + lr) * LD2 + c * 16 + g * 4]) = pk;
      }
    }
    // within-wave fence (Pl[w] is wave-private): P ds_writes drained, and no
    // hoisting of the PV ds_reads above this point (r15/r18-r25-validated).
    asm volatile("s_waitcnt lgkmcnt(0)" ::: "memory");
    __builtin_amdgcn_sched_barrier(0);

    // PV: 4 kv-chunks of 32; V fragments read ONCE, used by both q-groups
#pragma unroll
    for (int c32 = 0; c32 < 4; ++c32) {
      bf16x8 pf0 = *(const bf16x8*)(&P[lr * LD2 + c32 * 32 + g * 8]);
      bf16x8 pf1 = *(const bf16x8*)(&P[(16 + lr) * LD2 + c32 * 32 + g * 8]);
#pragma unroll
      for (int dt = 0; dt < 4; ++dt) {
        bf16x8 vf = *(const bf16x8*)(&Vt[(dt * 16 + lr) * LD2 + c32 * 32 + g * 8]);
        o[0][dt] = __builtin_amdgcn_mfma_f32_16x16x32_bf16(pf0, vf, o[0][dt], 0, 0, 0);
        o[1][dt] = __builtin_amdgcn_mfma_f32_16x16x32_bf16(pf1, vf, o[1][dt], 0, 0, 0);
      }
    }
    // drain the PV ds_reads of P before the next tile's P ds_writes
    asm volatile("s_waitcnt lgkmcnt(0)" ::: "memory");
    __builtin_amdgcn_sched_barrier(0);
  }
#pragma unroll
  for (int qh = 0; qh < 2; ++qh) {
    float inv = 1.0f / lrun[qh];
#pragma unroll
    for (int r = 0; r < 4; ++r) {
      float iq = __shfl(inv, (lane >> 4) * 4 + r, 64);
      int q = q0 + qh * 16 + g * 4 + r;
      unsigned short* op = O + ((long)(b * SEQ + q) * DMODEL) + h * DK;
#pragma unroll
      for (int dt = 0; dt < 4; ++dt) op[dt * 16 + lr] = f2bf(o[qh][dt][r] * iq);
    }
  }
}

// ---------------------------------------------------------------- launch
extern "C" void kernel_launch(void* const* d_in, const int* in_sizes, int n_in,
                              void* d_out, int out_size, void* d_ws, size_t ws_size,
                              hipStream_t stream) {
  const int* maskp = (const int*)d_in[3];
  float* out = (float*)d_out;

  char* ws = (char*)d_ws;
  const long MB = 1 << 20;
  unsigned long long* pm = (unsigned long long*)ws;             // 1 MB
  unsigned short* Qc  = (unsigned short*)(ws + 1 * MB);         // 8 MB each
  unsigned short* Kc  = (unsigned short*)(ws + 9 * MB);
  unsigned short* Vc  = (unsigned short*)(ws + 17 * MB);
  unsigned short* Wqc = (unsigned short*)(ws + 25 * MB);        // 2 MB each
  unsigned short* Wkc = (unsigned short*)(ws + 27 * MB);
  unsigned short* Wvc = (unsigned short*)(ws + 29 * MB);
  unsigned short* Woc = (unsigned short*)(ws + 31 * MB);
  unsigned short* bqc = (unsigned short*)(ws + 33 * MB);        // 2 KB each
  unsigned short* bkc = (unsigned short*)(ws + 33 * MB + 4096);
  unsigned short* bvc = (unsigned short*)(ws + 33 * MB + 8192);
  unsigned short* boc = (unsigned short*)(ws + 33 * MB + 12288);
  unsigned short* Qb  = (unsigned short*)(ws + 35 * MB);        // 8 MB each
  unsigned short* Kb  = (unsigned short*)(ws + 43 * MB);
  unsigned short* Vb  = (unsigned short*)(ws + 51 * MB);        // holds V^T
  unsigned short* Ab  = (unsigned short*)(ws + 59 * MB);

  prep<<<2561, 256, 0, stream>>>((const float*)d_in[0], (const float*)d_in[1],
                                 (const float*)d_in[2],
                                 (const float*)d_in[4], (const float*)d_in[6],
                                 (const float*)d_in[8], (const float*)d_in[10],
                                 (const float*)d_in[5], (const float*)d_in[7],
                                 (const float*)d_in[9], (const float*)d_in[11],
                                 maskp,
                                 Qc, Kc, Vc, Wqc, Wkc, Wvc, Woc,
                                 bqc, bkc, bvc, boc, pm);

  qkv_proj<<<768, 256, 0, stream>>>(Qc, Kc, Vc, Wqc, Wkc, Wvc,
                                    bqc, bkc, bvc, Qb, Kb, Vb);

  attn<<<BATCH * NH * (SEQ / 128), 256, 0, stream>>>(Qb, Kb, Vb, pm, Ab);

  gemm_out<<<256, 256, 0, stream>>>(Ab, Woc, boc, out);
}